// Round 11
// baseline (562.782 us; speedup 1.0000x reference)
//
#include <hip/hip_runtime.h>
#include <hip/hip_bf16.h>

#define HH 256
#define DD 64
#define SS 49
#define BB 4800
#define PP 16384
#define NDP 32768
#define KWO 12544  // S*H
#define MPAD 4864  // BB padded to 128
#define SK 8       // split-K factor for K5
#define KCH 1568   // KWO / SK = 49 * 32

typedef unsigned int u32;
typedef unsigned short u16;
typedef __attribute__((ext_vector_type(8))) short bf16x8;
typedef __attribute__((ext_vector_type(4))) float f32x4;

__device__ __forceinline__ float bf2f(__hip_bfloat16 h) { return __bfloat162float(h); }

__device__ __forceinline__ void load_lds16(const void* g, void* l) {
  __builtin_amdgcn_global_load_lds(
      (const __attribute__((address_space(1))) unsigned int*)g,
      (__attribute__((address_space(3))) unsigned int*)l, 16, 0, 0);
}

// permutation of the params N-dim: param1 (n=h*64+d) -> [d][h]; param2 -> [h][d]
__device__ __forceinline__ int nperm(int n) {
  if (n < PP) { int h = n >> 6, d = n & 63; return d * HH + h; }
  int r = n - PP; int d = r >> 8, h = r & 255; return PP + h * DD + d;
}

__device__ __forceinline__ float wave_sum64(float v) {
#pragma unroll
  for (int off = 32; off > 0; off >>= 1) v += __shfl_xor(v, off);
  return v;
}

__device__ __forceinline__ float block_sum256(float v, float* red) {
  v = wave_sum64(v);
  int w = threadIdx.x >> 6;
  if ((threadIdx.x & 63) == 0) red[w] = v;
  __syncthreads();
  float r = red[0] + red[1] + red[2] + red[3];
  __syncthreads();
  return r;
}

// K0: w2[k] = sum_h Wq[k][h]*bk[h]; c2 = sum_h bq[h]*bk[h]
__global__ void k0_prep(const float* __restrict__ Wq, const float* __restrict__ bk,
                        const float* __restrict__ bq, float* __restrict__ w2c2) {
  __shared__ float red[4];
  int k = blockIdx.x, h = threadIdx.x;
  float v = Wq[k * HH + h];
  float s = block_sum256(v * bk[h], red);
  if (h == 0) w2c2[k] = s;
  if (k == 0) {
    float s2 = block_sum256(bq[h] * bk[h], red);
    if (h == 0) w2c2[HH] = s2;
  }
}

// Prep k1 weights: z=0..3 transpose+cast {Wqs1,Wqs2,Wr1,Wk} -> [n][k] bf16; z=4 cast Wq.
__global__ __launch_bounds__(256) void kc_w1(
    const float* __restrict__ Wqs1, const float* __restrict__ Wqs2,
    const float* __restrict__ Wr1, const float* __restrict__ Wk,
    const float* __restrict__ Wq,
    u16* __restrict__ w1t, u16* __restrict__ w2t, u16* __restrict__ wr1t,
    u16* __restrict__ wkt, u16* __restrict__ wqh) {
  int t = threadIdx.x;
  int zi = blockIdx.z;
  if (zi == 4) {
    int row = blockIdx.y * 32 + (t >> 3), col = blockIdx.x * 32 + (t & 7) * 4;
    float4 v = *(const float4*)&Wq[row * HH + col];
    union { u16 u[4]; uint2 q; } pk;
    __hip_bfloat16 hb;
    hb = __float2bfloat16(v.x); pk.u[0] = *(u16*)&hb;
    hb = __float2bfloat16(v.y); pk.u[1] = *(u16*)&hb;
    hb = __float2bfloat16(v.z); pk.u[2] = *(u16*)&hb;
    hb = __float2bfloat16(v.w); pk.u[3] = *(u16*)&hb;
    *(uint2*)&wqh[row * HH + col] = pk.q;
    return;
  }
  const float* src = (zi == 0) ? Wqs1 : (zi == 1) ? Wqs2 : (zi == 2) ? Wr1 : Wk;
  u16* dst = (zi == 0) ? w1t : (zi == 1) ? w2t : (zi == 2) ? wr1t : wkt;
  __shared__ float tile[32][33];
  int n0 = blockIdx.x * 32, k0 = blockIdx.y * 32;
  {
    int kk = t >> 3, nn = (t & 7) * 4;
    float4 v = *(const float4*)&src[(k0 + kk) * HH + n0 + nn];
    tile[kk][nn + 0] = v.x;
    tile[kk][nn + 1] = v.y;
    tile[kk][nn + 2] = v.z;
    tile[kk][nn + 3] = v.w;
  }
  __syncthreads();
  {
    int nn = t >> 3, kk = (t & 7) * 4;
    union { u16 u[4]; uint2 q; } pk;
#pragma unroll
    for (int i = 0; i < 4; ++i) {
      __hip_bfloat16 hb = __float2bfloat16(tile[kk + i][nn]);
      pk.u[i] = *(u16*)&hb;
    }
    *(uint2*)&dst[(n0 + nn) * HH + k0 + kk] = pk.q;
  }
}

// ---- k1_mfma helpers: BM=64, 8 waves (2m x 4n), per-wave 32x64 output ----
__device__ __forceinline__ void g_gemm(const u16* aLb, const u16* __restrict__ Bg,
                                       int wm, int wn, int lg, int lr,
                                       f32x4 acc[2][4]) {
#pragma unroll
  for (int k0 = 0; k0 < HH; k0 += 32) {
    int colb = (k0 + (lg << 3)) << 1;
    bf16x8 af[2];
#pragma unroll
    for (int mi = 0; mi < 2; ++mi) {
      int row = wm * 32 + mi * 16 + lr;
      af[mi] = *(const bf16x8*)((const char*)aLb + (row << 9) +
                                (colb ^ ((row & 7) << 4)));
    }
    bf16x8 bfr[4];
#pragma unroll
    for (int ni = 0; ni < 4; ++ni) {
      int n = wn * 64 + ni * 16 + lr;
      bfr[ni] = *(const bf16x8*)&Bg[n * HH + k0 + (lg << 3)];
    }
#pragma unroll
    for (int mi = 0; mi < 2; ++mi)
#pragma unroll
      for (int ni = 0; ni < 4; ++ni)
        acc[mi][ni] = __builtin_amdgcn_mfma_f32_16x16x32_bf16(af[mi], bfr[ni], acc[mi][ni], 0, 0, 0);
  }
}

__device__ __forceinline__ void c_write(u16* xLb, f32x4 acc[2][4],
                                        const float* __restrict__ bias, bool dorelu,
                                        int wm, int wn, int lg, int lr) {
#pragma unroll
  for (int ni = 0; ni < 4; ++ni) {
    int col = wn * 64 + ni * 16 + lr;
    float bv = bias ? bias[col] : 0.f;
#pragma unroll
    for (int mi = 0; mi < 2; ++mi) {
#pragma unroll
      for (int j = 0; j < 4; ++j) {
        int row = wm * 32 + mi * 16 + (lg << 2) + j;
        float v = acc[mi][ni][j] + bv;
        if (dorelu) v = fmaxf(v, 0.f);
        __hip_bfloat16 hb = __float2bfloat16(v);
        *(u16*)((char*)xLb + (row << 9) + (((col << 1)) ^ ((row & 7) << 4))) = *(u16*)&hb;
      }
    }
  }
}

// K1: fused MLP chain via MFMA. BM=64, grid 75, 512 threads.
__global__ __launch_bounds__(512) void k1_mfma(
    const u16* __restrict__ proh, const float* __restrict__ posx,
    const float* __restrict__ bbox,
    const u16* __restrict__ w1t, const u16* __restrict__ w2t,
    const u16* __restrict__ wr1t, const u16* __restrict__ wkt,
    const u16* __restrict__ wqh,
    const float* __restrict__ bqs1, const float* __restrict__ bqs2,
    const float* __restrict__ br1, const float* __restrict__ Wr2,
    const float* __restrict__ br2, const float* __restrict__ bq,
    float* __restrict__ z, float* __restrict__ c1) {
  __shared__ u16 aL[16384];   // [64][512B] swz: pro, later px
  __shared__ u16 xL[16384];   // r1 -> t1 -> y
  __shared__ float red0[512], red1[512];
  __shared__ float scLoL[64], scHiL[64];
  const int t = threadIdx.x;
  const int w = t >> 6, l = t & 63;
  const int lg = l >> 4, lr = l & 15;
  const int wm = w >> 2, wn = w & 3;
  const int m0 = blockIdx.x * 64;

#pragma unroll
  for (int i = 0; i < 4; ++i) {
    int c = i * 512 + t;
    int a = c * 16;
    int row = a >> 9, x0 = a & 511;
    int src = (m0 + row) * HH + ((x0 ^ ((row & 7) << 4)) >> 1);
    load_lds16(proh + src, (char*)aL + (size_t)(i * 512 + (w << 6)) * 16);
  }
  __syncthreads();

  // G3: r1 = relu(pro @ Wr1 + br1) -> xL
  {
    f32x4 acc[2][4] = {};
    g_gemm(aL, wr1t, wm, wn, lg, lr, acc);
    c_write(xL, acc, br1, true, wm, wn, lg, lr);
  }
  __syncthreads();
  // G4: ref = sigmoid(r1 @ Wr2 + br2); per-row scales
  {
    int row = t & 63, seg = t >> 6;
    float s0 = 0.f, s1 = 0.f;
#pragma unroll 8
    for (int hh = 0; hh < 32; ++hh) {
      int h = seg * 32 + hh;
      float rv = bf2f(*(const __hip_bfloat16*)((const char*)xL + (row << 9) +
                                               (((h << 1)) ^ ((row & 7) << 4))));
      s0 = fmaf(rv, Wr2[h * 2 + 0], s0);
      s1 = fmaf(rv, Wr2[h * 2 + 1], s1);
    }
    red0[row * 8 + seg] = s0;
    red1[row * 8 + seg] = s1;
  }
  __syncthreads();
  if (t < 64) {
    float s0 = br2[0], s1 = br2[1];
#pragma unroll
    for (int k = 0; k < 8; ++k) {
      s0 += red0[t * 8 + k];
      s1 += red1[t * 8 + k];
    }
    float r0 = 1.f / (1.f + __expf(-s0));
    float r1 = 1.f / (1.f + __expf(-s1));
    scHiL[t] = r0 / bbox[(m0 + t) * 4 + 2];
    scLoL[t] = r1 / bbox[(m0 + t) * 4 + 3];
  }
  // G1: t1 = relu(pro @ Wqs1 + bqs1) -> xL (after barrier)
  f32x4 acc1[2][4] = {};
  g_gemm(aL, w1t, wm, wn, lg, lr, acc1);
  __syncthreads();
  c_write(xL, acc1, bqs1, true, wm, wn, lg, lr);
  __syncthreads();
  // G2: pos_t = t1 @ Wqs2 (+bqs2 later) -> regs
  f32x4 accp[2][4] = {};
  g_gemm(xL, w2t, wm, wn, lg, lr, accp);
  __syncthreads();
  // scale: px = posx * (pos_t+bqs2) * sc -> aL
#pragma unroll
  for (int ni = 0; ni < 4; ++ni) {
    int col = wn * 64 + ni * 16 + lr;
    float bv = bqs2[col];
#pragma unroll
    for (int mi = 0; mi < 2; ++mi) {
#pragma unroll
      for (int j = 0; j < 4; ++j) {
        int row = wm * 32 + mi * 16 + (lg << 2) + j;
        float pt = accp[mi][ni][j] + bv;
        float sc = (col < 128) ? scLoL[row] : scHiL[row];
        float v = posx[(m0 + row) * HH + col] * pt * sc;
        __hip_bfloat16 hb = __float2bfloat16(v);
        *(u16*)((char*)aL + (row << 9) + (((col << 1)) ^ ((row & 7) << 4))) = *(u16*)&hb;
      }
    }
  }
  __syncthreads();
  // G5: y = px @ Wk -> xL
  {
    f32x4 acc[2][4] = {};
    g_gemm(aL, wkt, wm, wn, lg, lr, acc);
    c_write(xL, acc, nullptr, false, wm, wn, lg, lr);
  }
  __syncthreads();
  // c1 partials + G6: z = y @ Wq^T
  {
    int row = t & 63, seg = t >> 6;
    float s0 = 0.f;
#pragma unroll 8
    for (int hh = 0; hh < 32; ++hh) {
      int h = seg * 32 + hh;
      float yv = bf2f(*(const __hip_bfloat16*)((const char*)xL + (row << 9) +
                                               (((h << 1)) ^ ((row & 7) << 4))));
      s0 = fmaf(yv, bq[h], s0);
    }
    red0[row * 8 + seg] = s0;
  }
  f32x4 accz[2][4] = {};
  g_gemm(xL, wqh, wm, wn, lg, lr, accz);
  __syncthreads();
  if (t < 64) {
    float s = 0.f;
#pragma unroll
    for (int k = 0; k < 8; ++k) s += red0[t * 8 + k];
    c1[m0 + t] = s;
  }
#pragma unroll
  for (int ni = 0; ni < 4; ++ni) {
    int col = wn * 64 + ni * 16 + lr;
#pragma unroll
    for (int mi = 0; mi < 2; ++mi) {
#pragma unroll
      for (int j = 0; j < 4; ++j) {
        int row = wm * 32 + mi * 16 + (lg << 2) + j;
        z[(size_t)(m0 + row) * HH + col] = accz[mi][ni][j];
      }
    }
  }
}

// K2: fp[b,s] = posl[s]*(pos_img[s,b]·z[b] + c1[b]) + pos_img[s,b]·w2 + c2
__global__ __launch_bounds__(256) void k2_fp(
    const float* __restrict__ posi, const float* __restrict__ posl,
    const float* __restrict__ z, const float* __restrict__ c1,
    const float* __restrict__ w2c2, float* __restrict__ fp) {
  int b = blockIdx.x, t = threadIdx.x;
  int l = t & 63, w = t >> 6;
  float4 zv = *(const float4*)&z[b * HH + l * 4];
  float4 wv = *(const float4*)&w2c2[l * 4];
  float c1b = c1[b];
  float c2 = w2c2[HH];
  for (int s = w; s < SS; s += 4) {
    float4 pi = *(const float4*)&posi[((size_t)s * BB + b) * HH + l * 4];
    float d1 = pi.x * zv.x + pi.y * zv.y + pi.z * zv.z + pi.w * zv.w;
    float d2 = pi.x * wv.x + pi.y * wv.y + pi.z * wv.z + pi.w * wv.w;
#pragma unroll
    for (int off = 32; off > 0; off >>= 1) {
      d1 += __shfl_xor(d1, off);
      d2 += __shfl_xor(d2, off);
    }
    if (l == 0) fp[b * SS + s] = posl[s] * (d1 + c1b) + d2 + c2;
  }
}

// cast pro -> bf16, padded to MPAD rows (zeros in pad)
__global__ __launch_bounds__(256) void kc_pro(const float* __restrict__ pro,
                                              u16* __restrict__ proh) {
  int tg = blockIdx.x * 256 + threadIdx.x;
  int e0 = tg * 8;
  int row = e0 >> 8;
  union { u16 u[8]; uint4 v; } pk;
  if (row < BB) {
    float4 v0 = *(const float4*)&pro[e0];
    float4 v1 = *(const float4*)&pro[e0 + 4];
    float vv[8] = {v0.x, v0.y, v0.z, v0.w, v1.x, v1.y, v1.z, v1.w};
#pragma unroll
    for (int i = 0; i < 8; ++i) {
      __hip_bfloat16 hb = __float2bfloat16(vv[i]);
      pk.u[i] = *(u16*)&hb;
    }
  } else {
    pk.v = make_uint4(0, 0, 0, 0);
  }
  *(uint4*)&proh[e0] = pk.v;
}

// transpose+cast Wd (256 x 32768 f32) -> wdt[nperm(n)][k] bf16
__global__ __launch_bounds__(256) void kc_wdt(const float* __restrict__ Wd,
                                              u16* __restrict__ wdt) {
  __shared__ float tile[32][33];
  int n0 = blockIdx.x * 32;
  int k0 = blockIdx.y * 32;
  int t = threadIdx.x;
  {
    int kk = t >> 3, nn = (t & 7) * 4;
    float4 v = *(const float4*)&Wd[(size_t)(k0 + kk) * NDP + n0 + nn];
    tile[kk][nn + 0] = v.x;
    tile[kk][nn + 1] = v.y;
    tile[kk][nn + 2] = v.z;
    tile[kk][nn + 3] = v.w;
  }
  __syncthreads();
  {
    int nn = t >> 3, kk = (t & 7) * 4;
    union { u16 u[4]; uint2 v; } pk;
#pragma unroll
    for (int i = 0; i < 4; ++i) {
      __hip_bfloat16 hb = __float2bfloat16(tile[kk + i][nn]);
      pk.u[i] = *(u16*)&hb;
    }
    int np = nperm(n0 + nn);
    *(uint2*)&wdt[(size_t)np * HH + k0 + kk] = pk.v;
  }
}

// bdp[nperm(n)] = bd[n]
__global__ void kc_bdp(const float* __restrict__ bd, float* __restrict__ bdp) {
  int n = blockIdx.x * 256 + threadIdx.x;
  bdp[nperm(n)] = bd[n];
}

// transpose+cast Wo (12544 x 256 f32) -> woT (256 x 12544 bf16)
__global__ __launch_bounds__(256) void kc_wot(const float* __restrict__ Wo,
                                              u16* __restrict__ wot) {
  __shared__ float tile[32][33];
  int k0 = blockIdx.x * 32;
  int n0 = blockIdx.y * 32;
  int t = threadIdx.x;
  {
    int kk = t >> 3, nn = (t & 7) * 4;
    float4 v = *(const float4*)&Wo[(size_t)(k0 + kk) * HH + n0 + nn];
    tile[kk][nn + 0] = v.x;
    tile[kk][nn + 1] = v.y;
    tile[kk][nn + 2] = v.z;
    tile[kk][nn + 3] = v.w;
  }
  __syncthreads();
  {
    int nn = t >> 3, kk = (t & 7) * 4;
    union { u16 u[4]; uint2 v; } pk;
#pragma unroll
    for (int i = 0; i < 4; ++i) {
      __hip_bfloat16 hb = __float2bfloat16(tile[kk + i][nn]);
      pk.u[i] = *(u16*)&hb;
    }
    *(uint2*)&wot[(size_t)(n0 + nn) * KWO + k0 + kk] = pk.v;
  }
}

// K3: params = proh @ wdt^T + bdp via bf16 MFMA. 128x128 tile, BK=32,
// 512 threads / 8 waves (4m x 2n, per-wave 32x64 -> acc[2][4]).
// Staging: waves 0-3 stage A (512 chunks), waves 4-7 stage B (512 chunks),
// 2 gload_lds per wave per K-step, wave-uniform LDS dests.
__global__ __launch_bounds__(512) void k3_mfma(const u16* __restrict__ proh,
                                               const u16* __restrict__ wdt,
                                               const float* __restrict__ bdp,
                                               u16* __restrict__ params) {
  __shared__ char smem[32768];
  u16* Al = (u16*)smem;           // [128][32] bf16 = 512 x 16B chunks
  u16* Bl = (u16*)(smem + 8192);  // [128][32] bf16 (rows = n)
  const int t = threadIdx.x;
  const int w = t >> 6, l = t & 63;
  const int lg = l >> 4, lr = l & 15;
  const int n0 = blockIdx.x * 128;
  const int m0 = blockIdx.y * 128;
  const int wm = w >> 1, wn = w & 1;
  f32x4 acc[2][4] = {};

  for (int k0 = 0; k0 < HH; k0 += 32) {
#pragma unroll
    for (int i = 0; i < 2; ++i) {
      int cbase = (w & 3) * 128 + i * 64;   // wave-uniform chunk base
      int c = cbase + l;                    // per-lane chunk id, 0..511
      int r = c >> 2, kq = (c & 3) * 8;
      if (w < 4)
        load_lds16(proh + (size_t)(m0 + r) * HH + k0 + kq,
                   (char*)Al + (size_t)cbase * 16);
      else
        load_lds16(wdt + (size_t)(n0 + r) * HH + k0 + kq,
                   (char*)Bl + (size_t)cbase * 16);
    }
    __syncthreads();
    bf16x8 af[2], bfr[4];
#pragma unroll
    for (int mi = 0; mi < 2; ++mi)
      af[mi] = *(const bf16x8*)&Al[(wm * 32 + mi * 16 + lr) * 32 + lg * 8];
#pragma unroll
    for (int ni = 0; ni < 4; ++ni)
      bfr[ni] = *(const bf16x8*)&Bl[(wn * 64 + ni * 16 + lr) * 32 + lg * 8];
#pragma unroll
    for (int mi = 0; mi < 2; ++mi)
#pragma unroll
      for (int ni = 0; ni < 4; ++ni)
        acc[mi][ni] = __builtin_amdgcn_mfma_f32_16x16x32_bf16(af[mi], bfr[ni], acc[mi][ni], 0, 0, 0);
    __syncthreads();
  }
  // epilogue: bias + bf16 -> full 128x128 LDS tile, then coalesced 16B stores
  u16* cb = (u16*)smem;  // [128][128] bf16 = 32 KB
#pragma unroll
  for (int ni = 0; ni < 4; ++ni) {
    int col = wn * 64 + ni * 16 + lr;
    float bias = bdp[n0 + col];
#pragma unroll
    for (int mi = 0; mi < 2; ++mi) {
#pragma unroll
      for (int j = 0; j < 4; ++j) {
        int row = wm * 32 + mi * 16 + (lg << 2) + j;
        __hip_bfloat16 hb = __float2bfloat16(acc[mi][ni][j] + bias);
        cb[row * 128 + col] = *(u16*)&hb;
      }
    }
  }
  __syncthreads();
#pragma unroll
  for (int i = 0; i < 4; ++i) {
    int idx = i * 512 + t;
    int row = idx >> 4, cc = (idx & 15) * 8;
    if (m0 + row < BB)
      *(uint4*)&params[(size_t)(m0 + row) * NDP + n0 + cc] = *(const uint4*)&cb[row * 128 + cc];
  }
}

// K4: per-b dynamic conv via MFMA. Halved staging: bufP 8KB + bufF 8KB -> 4 blocks/CU.
__global__ __launch_bounds__(256) void k4_mfma(
    const float* __restrict__ roi, const u16* __restrict__ params,
    const float* __restrict__ fpbuf,
    const float* __restrict__ g1, const float* __restrict__ be1,
    const float* __restrict__ g2, const float* __restrict__ be2,
    u16* __restrict__ f2ws) {
  __shared__ u16 bufP[8192];  // p1 h-half [64 d][128 h] swz(256B); later p2 h-half [128 h][64 d] swz(128B)
  __shared__ u16 bufF[8192];  // feat h-half [64 s][128 h] swz(256B); later f1L [64 s][64 d] swz(128B)
  __shared__ float fpL[64];
  __shared__ float g1L[64], b1L[64], g2L[256], b2L[256];

  const int b = blockIdx.x;
  const int t = threadIdx.x;
  const int w = t >> 6, l = t & 63;
  const int lg = l >> 4, lr = l & 15;
  const u16* p1g = params + (size_t)b * NDP;        // [64][256]
  const u16* p2g = params + (size_t)b * NDP + PP;   // [256][64]

  f32x4 acc1[4] = {};
#pragma unroll
  for (int half = 0; half < 2; ++half) {
    const int hoff = half * 128;
    // stage p1 h-half (512 chunks, 2/thread), pre-swizzled source, 256B rows
#pragma unroll
    for (int i = 0; i < 4; ++i) {
      int c = i * 256 + t;
      int row = c >> 4, x0 = (c & 15) * 16;
      load_lds16(p1g + row * HH + hoff + ((x0 ^ ((row & 7) << 4)) >> 1),
                 (char*)bufP + (size_t)(i * 256 + (w << 6)) * 16);
    }
    // feat h-half: fp32 -> bf16, swizzled ds_write (256B rows)
#pragma unroll
    for (int i = 0; i < 8; ++i) {
      int idx = i * 256 + t;
      int row = idx >> 5, c4 = (idx & 31) << 2;
      union { u16 u[4]; unsigned long long v; } pk;
      if (row < SS) {
        float4 v = *(const float4*)&roi[((size_t)row * BB + b) * HH + hoff + c4];
        __hip_bfloat16 h0 = __float2bfloat16(v.x), h1 = __float2bfloat16(v.y);
        __hip_bfloat16 h2 = __float2bfloat16(v.z), h3 = __float2bfloat16(v.w);
        pk.u[0] = *(u16*)&h0; pk.u[1] = *(u16*)&h1;
        pk.u[2] = *(u16*)&h2; pk.u[3] = *(u16*)&h3;
      } else {
        pk.v = 0ull;
      }
      int ab = (row << 8) + (((c4 << 1)) ^ ((row & 7) << 4));
      *(unsigned long long*)((char*)bufF + ab) = pk.v;
    }
    if (half == 0) {
      if (t < 64) {
        fpL[t] = (t < SS) ? fpbuf[b * SS + t] : 0.f;
        g1L[t] = g1[t];
        b1L[t] = be1[t];
      }
      g2L[t] = g2[t];
      b2L[t] = be2[t];
    }
    __syncthreads();
    // f1 partial GEMM over this h-half (K=128): M=64 s, N=64 d
#pragma unroll
    for (int kk = 0; kk < 128; kk += 32) {
      int arow = w * 16 + lr;
      const bf16x8 af = *(const bf16x8*)((const char*)bufF + (arow << 8) +
                                         ((((kk + (lg << 3)) << 1)) ^ ((arow & 7) << 4)));
      bf16x8 bfr[4];
#pragma unroll
      for (int ni = 0; ni < 4; ++ni) {
        int brow = ni * 16 + lr;
        bfr[ni] = *(const bf16x8*)((const char*)bufP + (brow << 8) +
                                   ((((kk + (lg << 3)) << 1)) ^ ((brow & 7) << 4)));
      }
#pragma unroll
      for (int ni = 0; ni < 4; ++ni)
        acc1[ni] = __builtin_amdgcn_mfma_f32_16x16x32_bf16(af, bfr[ni], acc1[ni], 0, 0, 0);
    }
    __syncthreads();  // bufP/bufF reads done; next half (or p2/f1L) overwrites
  }

  // issue stage of p2 h-half0 into bufP ([128 h][64 d], 128B rows); hides under LN1
#pragma unroll
  for (int i = 0; i < 4; ++i) {
    int c = i * 256 + t;
    int row = c >> 3, x0 = (c & 7) * 16;
    load_lds16(p2g + row * DD + ((x0 ^ ((row & 7) << 4)) >> 1),
               (char*)bufP + (size_t)(i * 256 + (w << 6)) * 16);
  }

  // LN1 + relu -> f1L (overlay bufF; 128B rows, swizzled)
  u16* f1L = bufF;
#pragma unroll
  for (int j = 0; j < 4; ++j) {
    int s = w * 16 + (lg << 2) + j;
    float fpv = fpL[s];
    float x[4], sum = 0.f, sq = 0.f;
#pragma unroll
    for (int ni = 0; ni < 4; ++ni) {
      x[ni] = acc1[ni][j] + fpv;
      sum += x[ni];
      sq += x[ni] * x[ni];
    }
#pragma unroll
    for (int off = 1; off < 16; off <<= 1) {
      sum += __shfl_xor(sum, off);
      sq += __shfl_xor(sq, off);
    }
    float m = sum * (1.f / 64.f);
    float rs = rsqrtf(sq * (1.f / 64.f) - m * m + 1e-5f);
#pragma unroll
    for (int ni = 0; ni < 4; ++ni) {
      int d = ni * 16 + lr;
      float o = fmaxf((x[ni] - m) * rs * g1L[d] + b1L[d], 0.f);
      __hip_bfloat16 hb = __float2bfloat16(o);
      *(u16*)((char*)f1L + (s << 7) + ((d << 1) ^ ((s & 7) << 4))) = *(u16*)&hb;
    }
  }
  __syncthreads();  // f1L written, p2h0 arrived

  // f2 = f1 @ param2, N=256 h in two halves of 128. K=64 d.
  f32x4 acc2[16] = {};
#pragma unroll
  for (int nh = 0; nh < 2; ++nh) {
    if (nh == 1) {
      __syncthreads();  // p2h0 reads done
#pragma unroll
      for (int i = 0; i < 4; ++i) {
        int c = i * 256 + t;
        int row = c >> 3, x0 = (c & 7) * 16;
        load_lds16(p2g + (128 + row) * DD + ((x0 ^ ((row & 7) << 4)) >> 1),
                   (char*)bufP + (size_t)(i * 256 + (w << 6)) * 16);
      }
      __syncthreads();
    }
#pragma unroll
    for (int kk = 0; kk < 64; kk += 32) {
      int arow = w * 16 + lr;
      const bf16x8 af = *(const bf16x8*)((const char*)f1L + (arow << 7) +
                                         ((((kk + (lg << 3)) << 1)) ^ ((arow & 7) << 4)));
#pragma unroll
      for (int ni = 0; ni < 8; ++ni) {
        int brow = ni * 16 + lr;
        const bf16x8 bfr = *(const bf16x8*)((const char*)bufP + (brow << 7) +
                                            ((((kk + (lg << 3)) << 1)) ^ ((brow & 7) << 4)));
        acc2[nh * 8 + ni] = __builtin_amdgcn_mfma_f32_16x16x32_bf16(af, bfr, acc2[nh * 8 + ni], 0, 0, 0);
      }
    }
  }

  // LN2 + relu -> f2ws
#pragma unroll
  for (int j = 0; j < 4; ++j) {
    int s = w * 16 + (lg << 2) + j;
    float sum = 0.f, sq = 0.f;
#pragma unroll
    for (int ni = 0; ni < 16; ++ni) {
      float v = acc2[ni][j];
      sum += v;
      sq += v * v;
    }
#pragma unroll
    for (int off = 1; off < 16; off <<= 1) {
      sum += __shfl_xor(sum, off);
      sq += __shfl_xor(sq, off);
    }
    float m = sum * (1.f / 256.f);
    float rs = rsqrtf(sq * (1.f / 256.f) - m * m + 1e-5f);
    if (s < SS) {
#pragma unroll
      for (int ni = 0; ni < 16; ++ni) {
        int h = ni * 16 + lr;
        float o = fmaxf((acc2[ni][j] - m) * rs * g2L[h] + b2L[h], 0.f);
        __hip_bfloat16 hb = __float2bfloat16(o);
        f2ws[(size_t)b * KWO + s * HH + h] = *(u16*)&hb;
      }
    }
  }
}

// K5: partial[sk][m][n] = f2ws[m, kchunk] @ woT[n, kchunk]^T, split-K bf16 MFMA.
__global__ __launch_bounds__(256) void k5_mfma(const u16* __restrict__ f2,
                                               const u16* __restrict__ wot,
                                               float* __restrict__ part) {
  __shared__ char smem[12288];
  u16* Al = (u16*)smem;
  u16* Bl = (u16*)(smem + 4096);
  const int t = threadIdx.x;
  const int w = t >> 6, l = t & 63;
  const int sk = blockIdx.x;
  const int m0 = blockIdx.y * 64;
  const int n0 = blockIdx.z * 128;
  const size_t kbase = (size_t)sk * KCH;
  const int wr = w >> 1, wc = w & 1;
  f32x4 acc[2][4] = {};

  for (int k0 = 0; k0 < KCH; k0 += 32) {
    {
      int r = t >> 2, kq = (t & 3) * 8;
      int wbase = (w << 6) * 8;
      load_lds16(f2 + (size_t)(m0 + r) * KWO + kbase + k0 + kq, Al + wbase);
    }
#pragma unroll
    for (int i = 0; i < 2; ++i) {
      int c = i * 256 + t;
      int r = c >> 2, kq = (c & 3) * 8;
      int wbase = (i * 256 + (w << 6)) * 8;
      load_lds16(wot + (size_t)(n0 + r) * KWO + kbase + k0 + kq, Bl + wbase);
    }
    __syncthreads();
    bf16x8 af[2], bfr[4];
#pragma unroll
    for (int mi = 0; mi < 2; ++mi)
      af[mi] = *(const bf16x8*)&Al[(wr * 32 + mi * 16 + (l & 15)) * 32 + (l >> 4) * 8];
#pragma unroll
    for (int ni = 0; ni < 4; ++ni)
      bfr[ni] = *(const bf16x8*)&Bl[(wc * 64 + ni * 16 + (l & 15)) * 32 + (l >> 4) * 8];
#pragma unroll
    for (int mi = 0; mi < 2; ++mi)
#pragma unroll
      for (int ni = 0; ni < 4; ++ni)
        acc[mi][ni] = __builtin_amdgcn_mfma_f32_16x16x32_bf16(af[mi], bfr[ni], acc[mi][ni], 0, 0, 0);
    __syncthreads();
  }
#pragma unroll
  for (int mi = 0; mi < 2; ++mi) {
#pragma unroll
    for (int j = 0; j < 4; ++j) {
      int m = m0 + wr * 32 + mi * 16 + ((l >> 4) << 2) + j;
#pragma unroll
      for (int ni = 0; ni < 4; ++ni) {
        int n = n0 + wc * 64 + ni * 16 + (l & 15);
        part[((size_t)sk * BB + m) * HH + n] = acc[mi][ni][j];
      }
    }
  }
}

// K5R: reduce partials + bias, LN3 + relu -> out
__global__ __launch_bounds__(256) void k5r_ln3(
    const float* __restrict__ part, const float* __restrict__ bo,
    const float* __restrict__ g3, const float* __restrict__ be3,
    float* __restrict__ out) {
  __shared__ float red[4];
  int b = blockIdx.x, t = threadIdx.x;
  float v = bo[t];
#pragma unroll
  for (int sk = 0; sk < SK; ++sk) v += part[((size_t)sk * BB + b) * HH + t];
  float m = block_sum256(v, red) * (1.f / HH);
  float d = v - m;
  float var = block_sum256(d * d, red) * (1.f / HH);
  out[b * HH + t] = fmaxf(fmaf(d * rsqrtf(var + 1e-5f), g3[t], be3[t]), 0.f);
}

extern "C" void kernel_launch(void* const* d_in, const int* in_sizes, int n_in,
                              void* d_out, int out_size, void* d_ws, size_t ws_size,
                              hipStream_t stream) {
  const float* pro  = (const float*)d_in[0];
  const float* roi  = (const float*)d_in[1];
  const float* posx = (const float*)d_in[2];
  const float* posi = (const float*)d_in[3];
  const float* posl = (const float*)d_in[4];
  const float* bbox = (const float*)d_in[5];
  const float* Wd   = (const float*)d_in[6];
  const float* bd   = (const float*)d_in[7];
  const float* Wqs1 = (const float*)d_in[8];
  const float* bqs1 = (const float*)d_in[9];
  const float* Wqs2 = (const float*)d_in[10];
  const float* bqs2 = (const float*)d_in[11];
  const float* Wr1  = (const float*)d_in[12];
  const float* br1  = (const float*)d_in[13];
  const float* Wr2  = (const float*)d_in[14];
  const float* br2  = (const float*)d_in[15];
  const float* Wq   = (const float*)d_in[16];
  const float* bq   = (const float*)d_in[17];
  const float* Wk   = (const float*)d_in[18];
  const float* bk   = (const float*)d_in[19];
  const float* g1   = (const float*)d_in[20];
  const float* be1  = (const float*)d_in[21];
  const float* g2   = (const float*)d_in[22];
  const float* be2  = (const float*)d_in[23];
  const float* g3   = (const float*)d_in[24];
  const float* be3  = (const float*)d_in[25];
  const float* Wo   = (const float*)d_in[26];
  const float* bo   = (const float*)d_in[27];

  char* ws = (char*)d_ws;
  u16* w1t  = (u16*)(ws + 0ull);
  u16* w2t  = (u16*)(ws + 131072ull);
  u16* wr1t = (u16*)(ws + 262144ull);
  u16* wkt  = (u16*)(ws + 393216ull);
  u16* wqh  = (u16*)(ws + 524288ull);
  u16* params = (u16*)(ws + 0ull);
  float* part = (float*)(ws + 0ull);
  u16* f2ws   = (u16*)(ws + 314572800ull);
  u16* proh   = (u16*)(ws + 314572800ull);
  u16* wdt    = (u16*)(ws + 317063168ull);
  float* z    = (float*)(ws + 434995200ull);
  u16* wot    = (u16*)(ws + 434995200ull);
  float* bdp  = (float*)(ws + 441417728ull);
  float* fp   = (float*)(ws + 444825600ull);
  float* c1   = (float*)(ws + 445766400ull);
  float* w2c2 = (float*)(ws + 446047744ull);

  kc_pro<<<dim3(MPAD * HH / 8 / 256), dim3(256), 0, stream>>>(pro, proh);
  kc_w1<<<dim3(8, 8, 5), dim3(256), 0, stream>>>(Wqs1, Wqs2, Wr1, Wk, Wq,
                                                 w1t, w2t, wr1t, wkt, wqh);
  k0_prep<<<dim3(256), dim3(256), 0, stream>>>(Wq, bk, bq, w2c2);
  k1_mfma<<<dim3(BB / 64), dim3(512), 0, stream>>>(proh, posx, bbox, w1t, w2t, wr1t,
                                                   wkt, wqh, bqs1, bqs2, br1, Wr2,
                                                   br2, bq, z, c1);
  k2_fp<<<dim3(BB), dim3(256), 0, stream>>>(posi, posl, z, c1, w2c2, fp);
  // z dead; wot overlays it
  kc_wot<<<dim3(KWO / 32, HH / 32), dim3(256), 0, stream>>>(Wo, wot);
  kc_wdt<<<dim3(NDP / 32, HH / 32), dim3(256), 0, stream>>>(Wd, wdt);
  kc_bdp<<<dim3(NDP / 256), dim3(256), 0, stream>>>(bd, bdp);
  // k1 weights dead; k3 overwrites params region
  k3_mfma<<<dim3(NDP / 128, MPAD / 128), dim3(512), 0, stream>>>(proh, wdt, bdp, params);
  k4_mfma<<<dim3(BB), dim3(256), 0, stream>>>(roi, params, fp, g1, be1, g2, be2, f2ws);
  // params dead; part overlays it
  k5_mfma<<<dim3(SK, BB / 64, HH / 128), dim3(256), 0, stream>>>(f2ws, wot, part);
  k5r_ln3<<<dim3(BB), dim3(256), 0, stream>>>(part, bo, g3, be3, (float*)d_out);
}

// Round 12
// 543.755 us; speedup vs baseline: 1.0350x; 1.0350x over previous
//
#include <hip/hip_runtime.h>
#include <hip/hip_bf16.h>

#define HH 256
#define DD 64
#define SS 49
#define BB 4800
#define PP 16384
#define NDP 32768
#define KWO 12544  // S*H
#define MPAD 4864  // BB padded to 128
#define SK 8       // split-K factor for K5
#define KCH 1568   // KWO / SK = 49 * 32

typedef unsigned int u32;
typedef unsigned short u16;
typedef __attribute__((ext_vector_type(8))) short bf16x8;
typedef __attribute__((ext_vector_type(4))) float f32x4;

__device__ __forceinline__ float bf2f(__hip_bfloat16 h) { return __bfloat162float(h); }

__device__ __forceinline__ void load_lds16(const void* g, void* l) {
  __builtin_amdgcn_global_load_lds(
      (const __attribute__((address_space(1))) unsigned int*)g,
      (__attribute__((address_space(3))) unsigned int*)l, 16, 0, 0);
}

// permutation of the params N-dim: param1 (n=h*64+d) -> [d][h]; param2 -> [h][d]
__device__ __forceinline__ int nperm(int n) {
  if (n < PP) { int h = n >> 6, d = n & 63; return d * HH + h; }
  int r = n - PP; int d = r >> 8, h = r & 255; return PP + h * DD + d;
}

__device__ __forceinline__ float wave_sum64(float v) {
#pragma unroll
  for (int off = 32; off > 0; off >>= 1) v += __shfl_xor(v, off);
  return v;
}

__device__ __forceinline__ float block_sum256(float v, float* red) {
  v = wave_sum64(v);
  int w = threadIdx.x >> 6;
  if ((threadIdx.x & 63) == 0) red[w] = v;
  __syncthreads();
  float r = red[0] + red[1] + red[2] + red[3];
  __syncthreads();
  return r;
}

// K0: w2[k] = sum_h Wq[k][h]*bk[h]; c2 = sum_h bq[h]*bk[h]
__global__ void k0_prep(const float* __restrict__ Wq, const float* __restrict__ bk,
                        const float* __restrict__ bq, float* __restrict__ w2c2) {
  __shared__ float red[4];
  int k = blockIdx.x, h = threadIdx.x;
  float v = Wq[k * HH + h];
  float s = block_sum256(v * bk[h], red);
  if (h == 0) w2c2[k] = s;
  if (k == 0) {
    float s2 = block_sum256(bq[h] * bk[h], red);
    if (h == 0) w2c2[HH] = s2;
  }
}

// Prep k1 weights: z=0..3 transpose+cast {Wqs1,Wqs2,Wr1,Wk} -> [n][k] bf16; z=4 cast Wq.
__global__ __launch_bounds__(256) void kc_w1(
    const float* __restrict__ Wqs1, const float* __restrict__ Wqs2,
    const float* __restrict__ Wr1, const float* __restrict__ Wk,
    const float* __restrict__ Wq,
    u16* __restrict__ w1t, u16* __restrict__ w2t, u16* __restrict__ wr1t,
    u16* __restrict__ wkt, u16* __restrict__ wqh) {
  int t = threadIdx.x;
  int zi = blockIdx.z;
  if (zi == 4) {
    int row = blockIdx.y * 32 + (t >> 3), col = blockIdx.x * 32 + (t & 7) * 4;
    float4 v = *(const float4*)&Wq[row * HH + col];
    union { u16 u[4]; uint2 q; } pk;
    __hip_bfloat16 hb;
    hb = __float2bfloat16(v.x); pk.u[0] = *(u16*)&hb;
    hb = __float2bfloat16(v.y); pk.u[1] = *(u16*)&hb;
    hb = __float2bfloat16(v.z); pk.u[2] = *(u16*)&hb;
    hb = __float2bfloat16(v.w); pk.u[3] = *(u16*)&hb;
    *(uint2*)&wqh[row * HH + col] = pk.q;
    return;
  }
  const float* src = (zi == 0) ? Wqs1 : (zi == 1) ? Wqs2 : (zi == 2) ? Wr1 : Wk;
  u16* dst = (zi == 0) ? w1t : (zi == 1) ? w2t : (zi == 2) ? wr1t : wkt;
  __shared__ float tile[32][33];
  int n0 = blockIdx.x * 32, k0 = blockIdx.y * 32;
  {
    int kk = t >> 3, nn = (t & 7) * 4;
    float4 v = *(const float4*)&src[(k0 + kk) * HH + n0 + nn];
    tile[kk][nn + 0] = v.x;
    tile[kk][nn + 1] = v.y;
    tile[kk][nn + 2] = v.z;
    tile[kk][nn + 3] = v.w;
  }
  __syncthreads();
  {
    int nn = t >> 3, kk = (t & 7) * 4;
    union { u16 u[4]; uint2 q; } pk;
#pragma unroll
    for (int i = 0; i < 4; ++i) {
      __hip_bfloat16 hb = __float2bfloat16(tile[kk + i][nn]);
      pk.u[i] = *(u16*)&hb;
    }
    *(uint2*)&dst[(n0 + nn) * HH + k0 + kk] = pk.q;
  }
}

// ---- k1_mfma helpers: BM=64, 8 waves (2m x 4n), per-wave 32x64 output ----
__device__ __forceinline__ void g_gemm(const u16* aLb, const u16* __restrict__ Bg,
                                       int wm, int wn, int lg, int lr,
                                       f32x4 acc[2][4]) {
#pragma unroll
  for (int k0 = 0; k0 < HH; k0 += 32) {
    int colb = (k0 + (lg << 3)) << 1;
    bf16x8 af[2];
#pragma unroll
    for (int mi = 0; mi < 2; ++mi) {
      int row = wm * 32 + mi * 16 + lr;
      af[mi] = *(const bf16x8*)((const char*)aLb + (row << 9) +
                                (colb ^ ((row & 7) << 4)));
    }
    bf16x8 bfr[4];
#pragma unroll
    for (int ni = 0; ni < 4; ++ni) {
      int n = wn * 64 + ni * 16 + lr;
      bfr[ni] = *(const bf16x8*)&Bg[n * HH + k0 + (lg << 3)];
    }
#pragma unroll
    for (int mi = 0; mi < 2; ++mi)
#pragma unroll
      for (int ni = 0; ni < 4; ++ni)
        acc[mi][ni] = __builtin_amdgcn_mfma_f32_16x16x32_bf16(af[mi], bfr[ni], acc[mi][ni], 0, 0, 0);
  }
}

__device__ __forceinline__ void c_write(u16* xLb, f32x4 acc[2][4],
                                        const float* __restrict__ bias, bool dorelu,
                                        int wm, int wn, int lg, int lr) {
#pragma unroll
  for (int ni = 0; ni < 4; ++ni) {
    int col = wn * 64 + ni * 16 + lr;
    float bv = bias ? bias[col] : 0.f;
#pragma unroll
    for (int mi = 0; mi < 2; ++mi) {
#pragma unroll
      for (int j = 0; j < 4; ++j) {
        int row = wm * 32 + mi * 16 + (lg << 2) + j;
        float v = acc[mi][ni][j] + bv;
        if (dorelu) v = fmaxf(v, 0.f);
        __hip_bfloat16 hb = __float2bfloat16(v);
        *(u16*)((char*)xLb + (row << 9) + (((col << 1)) ^ ((row & 7) << 4))) = *(u16*)&hb;
      }
    }
  }
}

// K1: fused MLP chain via MFMA. BM=64, grid 75, 512 threads.
__global__ __launch_bounds__(512) void k1_mfma(
    const u16* __restrict__ proh, const float* __restrict__ posx,
    const float* __restrict__ bbox,
    const u16* __restrict__ w1t, const u16* __restrict__ w2t,
    const u16* __restrict__ wr1t, const u16* __restrict__ wkt,
    const u16* __restrict__ wqh,
    const float* __restrict__ bqs1, const float* __restrict__ bqs2,
    const float* __restrict__ br1, const float* __restrict__ Wr2,
    const float* __restrict__ br2, const float* __restrict__ bq,
    float* __restrict__ z, float* __restrict__ c1) {
  __shared__ u16 aL[16384];   // [64][512B] swz: pro, later px
  __shared__ u16 xL[16384];   // r1 -> t1 -> y
  __shared__ float red0[512], red1[512];
  __shared__ float scLoL[64], scHiL[64];
  const int t = threadIdx.x;
  const int w = t >> 6, l = t & 63;
  const int lg = l >> 4, lr = l & 15;
  const int wm = w >> 2, wn = w & 3;
  const int m0 = blockIdx.x * 64;

#pragma unroll
  for (int i = 0; i < 4; ++i) {
    int c = i * 512 + t;
    int a = c * 16;
    int row = a >> 9, x0 = a & 511;
    int src = (m0 + row) * HH + ((x0 ^ ((row & 7) << 4)) >> 1);
    load_lds16(proh + src, (char*)aL + (size_t)(i * 512 + (w << 6)) * 16);
  }
  __syncthreads();

  // G3: r1 = relu(pro @ Wr1 + br1) -> xL
  {
    f32x4 acc[2][4] = {};
    g_gemm(aL, wr1t, wm, wn, lg, lr, acc);
    c_write(xL, acc, br1, true, wm, wn, lg, lr);
  }
  __syncthreads();
  // G4: ref = sigmoid(r1 @ Wr2 + br2); per-row scales
  {
    int row = t & 63, seg = t >> 6;
    float s0 = 0.f, s1 = 0.f;
#pragma unroll 8
    for (int hh = 0; hh < 32; ++hh) {
      int h = seg * 32 + hh;
      float rv = bf2f(*(const __hip_bfloat16*)((const char*)xL + (row << 9) +
                                               (((h << 1)) ^ ((row & 7) << 4))));
      s0 = fmaf(rv, Wr2[h * 2 + 0], s0);
      s1 = fmaf(rv, Wr2[h * 2 + 1], s1);
    }
    red0[row * 8 + seg] = s0;
    red1[row * 8 + seg] = s1;
  }
  __syncthreads();
  if (t < 64) {
    float s0 = br2[0], s1 = br2[1];
#pragma unroll
    for (int k = 0; k < 8; ++k) {
      s0 += red0[t * 8 + k];
      s1 += red1[t * 8 + k];
    }
    float r0 = 1.f / (1.f + __expf(-s0));
    float r1 = 1.f / (1.f + __expf(-s1));
    scHiL[t] = r0 / bbox[(m0 + t) * 4 + 2];
    scLoL[t] = r1 / bbox[(m0 + t) * 4 + 3];
  }
  // G1: t1 = relu(pro @ Wqs1 + bqs1) -> xL (after barrier)
  f32x4 acc1[2][4] = {};
  g_gemm(aL, w1t, wm, wn, lg, lr, acc1);
  __syncthreads();
  c_write(xL, acc1, bqs1, true, wm, wn, lg, lr);
  __syncthreads();
  // G2: pos_t = t1 @ Wqs2 (+bqs2 later) -> regs
  f32x4 accp[2][4] = {};
  g_gemm(xL, w2t, wm, wn, lg, lr, accp);
  __syncthreads();
  // scale: px = posx * (pos_t+bqs2) * sc -> aL
#pragma unroll
  for (int ni = 0; ni < 4; ++ni) {
    int col = wn * 64 + ni * 16 + lr;
    float bv = bqs2[col];
#pragma unroll
    for (int mi = 0; mi < 2; ++mi) {
#pragma unroll
      for (int j = 0; j < 4; ++j) {
        int row = wm * 32 + mi * 16 + (lg << 2) + j;
        float pt = accp[mi][ni][j] + bv;
        float sc = (col < 128) ? scLoL[row] : scHiL[row];
        float v = posx[(m0 + row) * HH + col] * pt * sc;
        __hip_bfloat16 hb = __float2bfloat16(v);
        *(u16*)((char*)aL + (row << 9) + (((col << 1)) ^ ((row & 7) << 4))) = *(u16*)&hb;
      }
    }
  }
  __syncthreads();
  // G5: y = px @ Wk -> xL
  {
    f32x4 acc[2][4] = {};
    g_gemm(aL, wkt, wm, wn, lg, lr, acc);
    c_write(xL, acc, nullptr, false, wm, wn, lg, lr);
  }
  __syncthreads();
  // c1 partials + G6: z = y @ Wq^T
  {
    int row = t & 63, seg = t >> 6;
    float s0 = 0.f;
#pragma unroll 8
    for (int hh = 0; hh < 32; ++hh) {
      int h = seg * 32 + hh;
      float yv = bf2f(*(const __hip_bfloat16*)((const char*)xL + (row << 9) +
                                               (((h << 1)) ^ ((row & 7) << 4))));
      s0 = fmaf(yv, bq[h], s0);
    }
    red0[row * 8 + seg] = s0;
  }
  f32x4 accz[2][4] = {};
  g_gemm(xL, wqh, wm, wn, lg, lr, accz);
  __syncthreads();
  if (t < 64) {
    float s = 0.f;
#pragma unroll
    for (int k = 0; k < 8; ++k) s += red0[t * 8 + k];
    c1[m0 + t] = s;
  }
#pragma unroll
  for (int ni = 0; ni < 4; ++ni) {
    int col = wn * 64 + ni * 16 + lr;
#pragma unroll
    for (int mi = 0; mi < 2; ++mi) {
#pragma unroll
      for (int j = 0; j < 4; ++j) {
        int row = wm * 32 + mi * 16 + (lg << 2) + j;
        z[(size_t)(m0 + row) * HH + col] = accz[mi][ni][j];
      }
    }
  }
}

// K2: fp[b,s] = posl[s]*(pos_img[s,b]·z[b] + c1[b]) + pos_img[s,b]·w2 + c2
__global__ __launch_bounds__(256) void k2_fp(
    const float* __restrict__ posi, const float* __restrict__ posl,
    const float* __restrict__ z, const float* __restrict__ c1,
    const float* __restrict__ w2c2, float* __restrict__ fp) {
  int b = blockIdx.x, t = threadIdx.x;
  int l = t & 63, w = t >> 6;
  float4 zv = *(const float4*)&z[b * HH + l * 4];
  float4 wv = *(const float4*)&w2c2[l * 4];
  float c1b = c1[b];
  float c2 = w2c2[HH];
  for (int s = w; s < SS; s += 4) {
    float4 pi = *(const float4*)&posi[((size_t)s * BB + b) * HH + l * 4];
    float d1 = pi.x * zv.x + pi.y * zv.y + pi.z * zv.z + pi.w * zv.w;
    float d2 = pi.x * wv.x + pi.y * wv.y + pi.z * wv.z + pi.w * wv.w;
#pragma unroll
    for (int off = 32; off > 0; off >>= 1) {
      d1 += __shfl_xor(d1, off);
      d2 += __shfl_xor(d2, off);
    }
    if (l == 0) fp[b * SS + s] = posl[s] * (d1 + c1b) + d2 + c2;
  }
}

// cast pro -> bf16, padded to MPAD rows (zeros in pad)
__global__ __launch_bounds__(256) void kc_pro(const float* __restrict__ pro,
                                              u16* __restrict__ proh) {
  int tg = blockIdx.x * 256 + threadIdx.x;
  int e0 = tg * 8;
  int row = e0 >> 8;
  union { u16 u[8]; uint4 v; } pk;
  if (row < BB) {
    float4 v0 = *(const float4*)&pro[e0];
    float4 v1 = *(const float4*)&pro[e0 + 4];
    float vv[8] = {v0.x, v0.y, v0.z, v0.w, v1.x, v1.y, v1.z, v1.w};
#pragma unroll
    for (int i = 0; i < 8; ++i) {
      __hip_bfloat16 hb = __float2bfloat16(vv[i]);
      pk.u[i] = *(u16*)&hb;
    }
  } else {
    pk.v = make_uint4(0, 0, 0, 0);
  }
  *(uint4*)&proh[e0] = pk.v;
}

// transpose+cast Wd (256 x 32768 f32) -> wdt[nperm(n)][k] bf16
__global__ __launch_bounds__(256) void kc_wdt(const float* __restrict__ Wd,
                                              u16* __restrict__ wdt) {
  __shared__ float tile[32][33];
  int n0 = blockIdx.x * 32;
  int k0 = blockIdx.y * 32;
  int t = threadIdx.x;
  {
    int kk = t >> 3, nn = (t & 7) * 4;
    float4 v = *(const float4*)&Wd[(size_t)(k0 + kk) * NDP + n0 + nn];
    tile[kk][nn + 0] = v.x;
    tile[kk][nn + 1] = v.y;
    tile[kk][nn + 2] = v.z;
    tile[kk][nn + 3] = v.w;
  }
  __syncthreads();
  {
    int nn = t >> 3, kk = (t & 7) * 4;
    union { u16 u[4]; uint2 v; } pk;
#pragma unroll
    for (int i = 0; i < 4; ++i) {
      __hip_bfloat16 hb = __float2bfloat16(tile[kk + i][nn]);
      pk.u[i] = *(u16*)&hb;
    }
    int np = nperm(n0 + nn);
    *(uint2*)&wdt[(size_t)np * HH + k0 + kk] = pk.v;
  }
}

// bdp[nperm(n)] = bd[n]
__global__ void kc_bdp(const float* __restrict__ bd, float* __restrict__ bdp) {
  int n = blockIdx.x * 256 + threadIdx.x;
  bdp[nperm(n)] = bd[n];
}

// transpose+cast Wo (12544 x 256 f32) -> woT (256 x 12544 bf16)
__global__ __launch_bounds__(256) void kc_wot(const float* __restrict__ Wo,
                                              u16* __restrict__ wot) {
  __shared__ float tile[32][33];
  int k0 = blockIdx.x * 32;
  int n0 = blockIdx.y * 32;
  int t = threadIdx.x;
  {
    int kk = t >> 3, nn = (t & 7) * 4;
    float4 v = *(const float4*)&Wo[(size_t)(k0 + kk) * HH + n0 + nn];
    tile[kk][nn + 0] = v.x;
    tile[kk][nn + 1] = v.y;
    tile[kk][nn + 2] = v.z;
    tile[kk][nn + 3] = v.w;
  }
  __syncthreads();
  {
    int nn = t >> 3, kk = (t & 7) * 4;
    union { u16 u[4]; uint2 v; } pk;
#pragma unroll
    for (int i = 0; i < 4; ++i) {
      __hip_bfloat16 hb = __float2bfloat16(tile[kk + i][nn]);
      pk.u[i] = *(u16*)&hb;
    }
    *(uint2*)&wot[(size_t)(n0 + nn) * KWO + k0 + kk] = pk.v;
  }
}

// K3: params = proh @ wdt^T + bdp via bf16 MFMA. M=4800(pad 4864), N=32768, K=256.
// (r8's measured-best version: 256 threads, BK=32, linear LDS.)
__global__ __launch_bounds__(256) void k3_mfma(const u16* __restrict__ proh,
                                               const u16* __restrict__ wdt,
                                               const float* __restrict__ bdp,
                                               u16* __restrict__ params) {
  __shared__ char smem[32768];
  u16* Al = (u16*)smem;
  u16* Bl = (u16*)(smem + 8192);
  const int t = threadIdx.x;
  const int w = t >> 6, l = t & 63;
  const int n0 = blockIdx.x * 128;
  const int m0 = blockIdx.y * 128;
  const int wr = w >> 1, wc = w & 1;
  f32x4 acc[4][4] = {};

  for (int k0 = 0; k0 < HH; k0 += 32) {
#pragma unroll
    for (int i = 0; i < 2; ++i) {
      int c = i * 256 + t;
      int r = c >> 2, kq = (c & 3) * 8;
      int wbase = (i * 256 + (w << 6)) * 8;
      load_lds16(proh + (size_t)(m0 + r) * HH + k0 + kq, Al + wbase);
      load_lds16(wdt + (size_t)(n0 + r) * HH + k0 + kq, Bl + wbase);
    }
    __syncthreads();
    bf16x8 af[4], bfr[4];
#pragma unroll
    for (int mi = 0; mi < 4; ++mi)
      af[mi] = *(const bf16x8*)&Al[(wr * 64 + mi * 16 + (l & 15)) * 32 + (l >> 4) * 8];
#pragma unroll
    for (int ni = 0; ni < 4; ++ni)
      bfr[ni] = *(const bf16x8*)&Bl[(wc * 64 + ni * 16 + (l & 15)) * 32 + (l >> 4) * 8];
#pragma unroll
    for (int mi = 0; mi < 4; ++mi)
#pragma unroll
      for (int ni = 0; ni < 4; ++ni)
        acc[mi][ni] = __builtin_amdgcn_mfma_f32_16x16x32_bf16(af[mi], bfr[ni], acc[mi][ni], 0, 0, 0);
    __syncthreads();
  }
  u16* cb = (u16*)smem;
#pragma unroll
  for (int ni = 0; ni < 4; ++ni) {
    int col = wc * 64 + ni * 16 + (l & 15);
    float bias = bdp[n0 + col];
#pragma unroll
    for (int mi = 0; mi < 4; ++mi) {
#pragma unroll
      for (int j = 0; j < 4; ++j) {
        int row = wr * 64 + mi * 16 + ((l >> 4) << 2) + j;
        __hip_bfloat16 hb = __float2bfloat16(acc[mi][ni][j] + bias);
        cb[row * 128 + col] = *(u16*)&hb;
      }
    }
  }
  __syncthreads();
#pragma unroll
  for (int i = 0; i < 8; ++i) {
    int idx = i * 256 + t;
    int row = idx >> 4, cc = (idx & 15) * 8;
    if (m0 + row < BB)
      *(uint4*)&params[(size_t)(m0 + row) * NDP + n0 + cc] = *(const uint4*)&cb[row * 128 + cc];
  }
}

// K4: per-b dynamic conv via MFMA. Halved staging: bufP 8KB + bufF 8KB -> 4 blocks/CU.
__global__ __launch_bounds__(256) void k4_mfma(
    const float* __restrict__ roi, const u16* __restrict__ params,
    const float* __restrict__ fpbuf,
    const float* __restrict__ g1, const float* __restrict__ be1,
    const float* __restrict__ g2, const float* __restrict__ be2,
    u16* __restrict__ f2ws) {
  __shared__ u16 bufP[8192];  // p1 h-half [64 d][128 h] swz(256B); later p2 h-half [128 h][64 d] swz(128B)
  __shared__ u16 bufF[8192];  // feat h-half [64 s][128 h] swz(256B); later f1L [64 s][64 d] swz(128B)
  __shared__ float fpL[64];
  __shared__ float g1L[64], b1L[64], g2L[256], b2L[256];

  const int b = blockIdx.x;
  const int t = threadIdx.x;
  const int w = t >> 6, l = t & 63;
  const int lg = l >> 4, lr = l & 15;
  const u16* p1g = params + (size_t)b * NDP;        // [64][256]
  const u16* p2g = params + (size_t)b * NDP + PP;   // [256][64]

  f32x4 acc1[4] = {};
#pragma unroll
  for (int half = 0; half < 2; ++half) {
    const int hoff = half * 128;
#pragma unroll
    for (int i = 0; i < 4; ++i) {
      int c = i * 256 + t;
      int row = c >> 4, x0 = (c & 15) * 16;
      load_lds16(p1g + row * HH + hoff + ((x0 ^ ((row & 7) << 4)) >> 1),
                 (char*)bufP + (size_t)(i * 256 + (w << 6)) * 16);
    }
#pragma unroll
    for (int i = 0; i < 8; ++i) {
      int idx = i * 256 + t;
      int row = idx >> 5, c4 = (idx & 31) << 2;
      union { u16 u[4]; unsigned long long v; } pk;
      if (row < SS) {
        float4 v = *(const float4*)&roi[((size_t)row * BB + b) * HH + hoff + c4];
        __hip_bfloat16 h0 = __float2bfloat16(v.x), h1 = __float2bfloat16(v.y);
        __hip_bfloat16 h2 = __float2bfloat16(v.z), h3 = __float2bfloat16(v.w);
        pk.u[0] = *(u16*)&h0; pk.u[1] = *(u16*)&h1;
        pk.u[2] = *(u16*)&h2; pk.u[3] = *(u16*)&h3;
      } else {
        pk.v = 0ull;
      }
      int ab = (row << 8) + (((c4 << 1)) ^ ((row & 7) << 4));
      *(unsigned long long*)((char*)bufF + ab) = pk.v;
    }
    if (half == 0) {
      if (t < 64) {
        fpL[t] = (t < SS) ? fpbuf[b * SS + t] : 0.f;
        g1L[t] = g1[t];
        b1L[t] = be1[t];
      }
      g2L[t] = g2[t];
      b2L[t] = be2[t];
    }
    __syncthreads();
#pragma unroll
    for (int kk = 0; kk < 128; kk += 32) {
      int arow = w * 16 + lr;
      const bf16x8 af = *(const bf16x8*)((const char*)bufF + (arow << 8) +
                                         ((((kk + (lg << 3)) << 1)) ^ ((arow & 7) << 4)));
      bf16x8 bfr[4];
#pragma unroll
      for (int ni = 0; ni < 4; ++ni) {
        int brow = ni * 16 + lr;
        bfr[ni] = *(const bf16x8*)((const char*)bufP + (brow << 8) +
                                   ((((kk + (lg << 3)) << 1)) ^ ((brow & 7) << 4)));
      }
#pragma unroll
      for (int ni = 0; ni < 4; ++ni)
        acc1[ni] = __builtin_amdgcn_mfma_f32_16x16x32_bf16(af, bfr[ni], acc1[ni], 0, 0, 0);
    }
    __syncthreads();
  }

#pragma unroll
  for (int i = 0; i < 4; ++i) {
    int c = i * 256 + t;
    int row = c >> 3, x0 = (c & 7) * 16;
    load_lds16(p2g + row * DD + ((x0 ^ ((row & 7) << 4)) >> 1),
               (char*)bufP + (size_t)(i * 256 + (w << 6)) * 16);
  }

  u16* f1L = bufF;
#pragma unroll
  for (int j = 0; j < 4; ++j) {
    int s = w * 16 + (lg << 2) + j;
    float fpv = fpL[s];
    float x[4], sum = 0.f, sq = 0.f;
#pragma unroll
    for (int ni = 0; ni < 4; ++ni) {
      x[ni] = acc1[ni][j] + fpv;
      sum += x[ni];
      sq += x[ni] * x[ni];
    }
#pragma unroll
    for (int off = 1; off < 16; off <<= 1) {
      sum += __shfl_xor(sum, off);
      sq += __shfl_xor(sq, off);
    }
    float m = sum * (1.f / 64.f);
    float rs = rsqrtf(sq * (1.f / 64.f) - m * m + 1e-5f);
#pragma unroll
    for (int ni = 0; ni < 4; ++ni) {
      int d = ni * 16 + lr;
      float o = fmaxf((x[ni] - m) * rs * g1L[d] + b1L[d], 0.f);
      __hip_bfloat16 hb = __float2bfloat16(o);
      *(u16*)((char*)f1L + (s << 7) + ((d << 1) ^ ((s & 7) << 4))) = *(u16*)&hb;
    }
  }
  __syncthreads();

  f32x4 acc2[16] = {};
#pragma unroll
  for (int nh = 0; nh < 2; ++nh) {
    if (nh == 1) {
      __syncthreads();
#pragma unroll
      for (int i = 0; i < 4; ++i) {
        int c = i * 256 + t;
        int row = c >> 3, x0 = (c & 7) * 16;
        load_lds16(p2g + (128 + row) * DD + ((x0 ^ ((row & 7) << 4)) >> 1),
                   (char*)bufP + (size_t)(i * 256 + (w << 6)) * 16);
      }
      __syncthreads();
    }
#pragma unroll
    for (int kk = 0; kk < 64; kk += 32) {
      int arow = w * 16 + lr;
      const bf16x8 af = *(const bf16x8*)((const char*)f1L + (arow << 7) +
                                         ((((kk + (lg << 3)) << 1)) ^ ((arow & 7) << 4)));
#pragma unroll
      for (int ni = 0; ni < 8; ++ni) {
        int brow = ni * 16 + lr;
        const bf16x8 bfr = *(const bf16x8*)((const char*)bufP + (brow << 7) +
                                            ((((kk + (lg << 3)) << 1)) ^ ((brow & 7) << 4)));
        acc2[nh * 8 + ni] = __builtin_amdgcn_mfma_f32_16x16x32_bf16(af, bfr, acc2[nh * 8 + ni], 0, 0, 0);
      }
    }
  }

#pragma unroll
  for (int j = 0; j < 4; ++j) {
    int s = w * 16 + (lg << 2) + j;
    float sum = 0.f, sq = 0.f;
#pragma unroll
    for (int ni = 0; ni < 16; ++ni) {
      float v = acc2[ni][j];
      sum += v;
      sq += v * v;
    }
#pragma unroll
    for (int off = 1; off < 16; off <<= 1) {
      sum += __shfl_xor(sum, off);
      sq += __shfl_xor(sq, off);
    }
    float m = sum * (1.f / 256.f);
    float rs = rsqrtf(sq * (1.f / 256.f) - m * m + 1e-5f);
    if (s < SS) {
#pragma unroll
      for (int ni = 0; ni < 16; ++ni) {
        int h = ni * 16 + lr;
        float o = fmaxf((acc2[ni][j] - m) * rs * g2L[h] + b2L[h], 0.f);
        __hip_bfloat16 hb = __float2bfloat16(o);
        f2ws[(size_t)b * KWO + s * HH + h] = *(u16*)&hb;
      }
    }
  }
}

// K5: partial[sk][m][0..256) = f2ws[m, kchunk] @ woT^T, split-K bf16 MFMA.
// BM=64, BN=256 (full width -> halves f2ws re-reads), BK=32. grid (SK, 75).
// 4 waves as 2m x 2n; per-wave 32m x 128n -> acc[2][8].
__global__ __launch_bounds__(256) void k5_mfma(const u16* __restrict__ f2,
                                               const u16* __restrict__ wot,
                                               float* __restrict__ part) {
  __shared__ char smem[20480];
  u16* Al = (u16*)smem;           // [64][32] bf16 = 4 KB
  u16* Bl = (u16*)(smem + 4096);  // [256][32] bf16 = 16 KB (rows = n)
  const int t = threadIdx.x;
  const int w = t >> 6, l = t & 63;
  const int lg = l >> 4, lr = l & 15;
  const int sk = blockIdx.x;
  const int m0 = blockIdx.y * 64;
  const size_t kbase = (size_t)sk * KCH;
  const int wr = w >> 1, wc = w & 1;
  f32x4 acc[2][8] = {};

  for (int k0 = 0; k0 < KCH; k0 += 32) {
    {
      // A: 64 rows x 32 k = 256 chunks, 1/thread
      int r = t >> 2, kq = (t & 3) * 8;
      int wbase = (w << 6) * 8;
      load_lds16(f2 + (size_t)(m0 + r) * KWO + kbase + k0 + kq, Al + wbase);
    }
#pragma unroll
    for (int i = 0; i < 4; ++i) {
      // B: 256 rows x 32 k = 1024 chunks, 4/thread
      int c = i * 256 + t;
      int r = c >> 2, kq = (c & 3) * 8;
      int wbase = (i * 256 + (w << 6)) * 8;
      load_lds16(wot + (size_t)r * KWO + kbase + k0 + kq, Bl + wbase);
    }
    __syncthreads();
    bf16x8 af[2], bfr[8];
#pragma unroll
    for (int mi = 0; mi < 2; ++mi)
      af[mi] = *(const bf16x8*)&Al[(wr * 32 + mi * 16 + lr) * 32 + lg * 8];
#pragma unroll
    for (int ni = 0; ni < 8; ++ni)
      bfr[ni] = *(const bf16x8*)&Bl[(wc * 128 + ni * 16 + lr) * 32 + lg * 8];
#pragma unroll
    for (int mi = 0; mi < 2; ++mi)
#pragma unroll
      for (int ni = 0; ni < 8; ++ni)
        acc[mi][ni] = __builtin_amdgcn_mfma_f32_16x16x32_bf16(af[mi], bfr[ni], acc[mi][ni], 0, 0, 0);
    __syncthreads();
  }
#pragma unroll
  for (int mi = 0; mi < 2; ++mi) {
#pragma unroll
    for (int j = 0; j < 4; ++j) {
      int m = m0 + wr * 32 + mi * 16 + (lg << 2) + j;
#pragma unroll
      for (int ni = 0; ni < 8; ++ni) {
        int n = wc * 128 + ni * 16 + lr;
        part[((size_t)sk * BB + m) * HH + n] = acc[mi][ni][j];
      }
    }
  }
}

// K5R: reduce partials + bias, LN3 + relu -> out
__global__ __launch_bounds__(256) void k5r_ln3(
    const float* __restrict__ part, const float* __restrict__ bo,
    const float* __restrict__ g3, const float* __restrict__ be3,
    float* __restrict__ out) {
  __shared__ float red[4];
  int b = blockIdx.x, t = threadIdx.x;
  float v = bo[t];
#pragma unroll
  for (int sk = 0; sk < SK; ++sk) v += part[((size_t)sk * BB + b) * HH + t];
  float m = block_sum256(v, red) * (1.f / HH);
  float d = v - m;
  float var = block_sum256(d * d, red) * (1.f / HH);
  out[b * HH + t] = fmaxf(fmaf(d * rsqrtf(var + 1e-5f), g3[t], be3[t]), 0.f);
}

extern "C" void kernel_launch(void* const* d_in, const int* in_sizes, int n_in,
                              void* d_out, int out_size, void* d_ws, size_t ws_size,
                              hipStream_t stream) {
  const float* pro  = (const float*)d_in[0];
  const float* roi  = (const float*)d_in[1];
  const float* posx = (const float*)d_in[2];
  const float* posi = (const float*)d_in[3];
  const float* posl = (const float*)d_in[4];
  const float* bbox = (const float*)d_in[5];
  const float* Wd   = (const float*)d_in[6];
  const float* bd   = (const float*)d_in[7];
  const float* Wqs1 = (const float*)d_in[8];
  const float* bqs1 = (const float*)d_in[9];
  const float* Wqs2 = (const float*)d_in[10];
  const float* bqs2 = (const float*)d_in[11];
  const float* Wr1  = (const float*)d_in[12];
  const float* br1  = (const float*)d_in[13];
  const float* Wr2  = (const float*)d_in[14];
  const float* br2  = (const float*)d_in[15];
  const float* Wq   = (const float*)d_in[16];
  const float* bq   = (const float*)d_in[17];
  const float* Wk   = (const float*)d_in[18];
  const float* bk   = (const float*)d_in[19];
  const float* g1   = (const float*)d_in[20];
  const float* be1  = (const float*)d_in[21];
  const float* g2   = (const float*)d_in[22];
  const float* be2  = (const float*)d_in[23];
  const float* g3   = (const float*)d_in[24];
  const float* be3  = (const float*)d_in[25];
  const float* Wo   = (const float*)d_in[26];
  const float* bo   = (const float*)d_in[27];

  char* ws = (char*)d_ws;
  u16* w1t  = (u16*)(ws + 0ull);
  u16* w2t  = (u16*)(ws + 131072ull);
  u16* wr1t = (u16*)(ws + 262144ull);
  u16* wkt  = (u16*)(ws + 393216ull);
  u16* wqh  = (u16*)(ws + 524288ull);
  u16* params = (u16*)(ws + 0ull);
  float* part = (float*)(ws + 0ull);
  u16* f2ws   = (u16*)(ws + 314572800ull);
  u16* proh   = (u16*)(ws + 314572800ull);
  u16* wdt    = (u16*)(ws + 317063168ull);
  float* z    = (float*)(ws + 434995200ull);
  u16* wot    = (u16*)(ws + 434995200ull);
  float* bdp  = (float*)(ws + 441417728ull);
  float* fp   = (float*)(ws + 444825600ull);
  float* c1   = (float*)(ws + 445766400ull);
  float* w2c2 = (float*)(ws + 446047744ull);

  kc_pro<<<dim3(MPAD * HH / 8 / 256), dim3(256), 0, stream>>>(pro, proh);
  kc_w1<<<dim3(8, 8, 5), dim3(256), 0, stream>>>(Wqs1, Wqs2, Wr1, Wk, Wq,
                                                 w1t, w2t, wr1t, wkt, wqh);
  k0_prep<<<dim3(256), dim3(256), 0, stream>>>(Wq, bk, bq, w2c2);
  k1_mfma<<<dim3(BB / 64), dim3(512), 0, stream>>>(proh, posx, bbox, w1t, w2t, wr1t,
                                                   wkt, wqh, bqs1, bqs2, br1, Wr2,
                                                   br2, bq, z, c1);
  k2_fp<<<dim3(BB), dim3(256), 0, stream>>>(posi, posl, z, c1, w2c2, fp);
  // z dead; wot overlays it
  kc_wot<<<dim3(KWO / 32, HH / 32), dim3(256), 0, stream>>>(Wo, wot);
  kc_wdt<<<dim3(NDP / 32, HH / 32), dim3(256), 0, stream>>>(Wd, wdt);
  kc_bdp<<<dim3(NDP / 256), dim3(256), 0, stream>>>(bd, bdp);
  // k1 weights dead; k3 overwrites params region
  k3_mfma<<<dim3(NDP / 128, MPAD / 128), dim3(256), 0, stream>>>(proh, wdt, bdp, params);
  k4_mfma<<<dim3(BB), dim3(256), 0, stream>>>(roi, params, fp, g1, be1, g2, be2, f2ws);
  // params dead; part overlays it
  k5_mfma<<<dim3(SK, BB / 64), dim3(256), 0, stream>>>(f2ws, wot, part);
  k5r_ln3<<<dim3(BB), dim3(256), 0, stream>>>(part, bo, g3, be3, (float*)d_out);
}

// Round 13
// 542.768 us; speedup vs baseline: 1.0369x; 1.0018x over previous
//
#include <hip/hip_runtime.h>
#include <hip/hip_bf16.h>

#define HH 256
#define DD 64
#define SS 49
#define BB 4800
#define PP 16384
#define NDP 32768
#define KWO 12544  // S*H
#define MPAD 4864  // BB padded to 128
#define SK 8       // split-K factor for K5
#define KCH 1568   // KWO / SK = 49 * 32

typedef unsigned int u32;
typedef unsigned short u16;
typedef __attribute__((ext_vector_type(8))) short bf16x8;
typedef __attribute__((ext_vector_type(4))) float f32x4;

__device__ __forceinline__ float bf2f(__hip_bfloat16 h) { return __bfloat162float(h); }

__device__ __forceinline__ void load_lds16(const void* g, void* l) {
  __builtin_amdgcn_global_load_lds(
      (const __attribute__((address_space(1))) unsigned int*)g,
      (__attribute__((address_space(3))) unsigned int*)l, 16, 0, 0);
}

// permutation of the params N-dim: param1 (n=h*64+d) -> [d][h]; param2 -> [h][d]
__device__ __forceinline__ int nperm(int n) {
  if (n < PP) { int h = n >> 6, d = n & 63; return d * HH + h; }
  int r = n - PP; int d = r >> 8, h = r & 255; return PP + h * DD + d;
}

__device__ __forceinline__ float wave_sum64(float v) {
#pragma unroll
  for (int off = 32; off > 0; off >>= 1) v += __shfl_xor(v, off);
  return v;
}

__device__ __forceinline__ float block_sum256(float v, float* red) {
  v = wave_sum64(v);
  int w = threadIdx.x >> 6;
  if ((threadIdx.x & 63) == 0) red[w] = v;
  __syncthreads();
  float r = red[0] + red[1] + red[2] + red[3];
  __syncthreads();
  return r;
}

// K0: w2[k] = sum_h Wq[k][h]*bk[h]; c2 = sum_h bq[h]*bk[h]
__global__ void k0_prep(const float* __restrict__ Wq, const float* __restrict__ bk,
                        const float* __restrict__ bq, float* __restrict__ w2c2) {
  __shared__ float red[4];
  int k = blockIdx.x, h = threadIdx.x;
  float v = Wq[k * HH + h];
  float s = block_sum256(v * bk[h], red);
  if (h == 0) w2c2[k] = s;
  if (k == 0) {
    float s2 = block_sum256(bq[h] * bk[h], red);
    if (h == 0) w2c2[HH] = s2;
  }
}

// Prep k1 weights: z=0..3 transpose+cast {Wqs1,Wqs2,Wr1,Wk} -> [n][k] bf16; z=4 cast Wq.
__global__ __launch_bounds__(256) void kc_w1(
    const float* __restrict__ Wqs1, const float* __restrict__ Wqs2,
    const float* __restrict__ Wr1, const float* __restrict__ Wk,
    const float* __restrict__ Wq,
    u16* __restrict__ w1t, u16* __restrict__ w2t, u16* __restrict__ wr1t,
    u16* __restrict__ wkt, u16* __restrict__ wqh) {
  int t = threadIdx.x;
  int zi = blockIdx.z;
  if (zi == 4) {
    int row = blockIdx.y * 32 + (t >> 3), col = blockIdx.x * 32 + (t & 7) * 4;
    float4 v = *(const float4*)&Wq[row * HH + col];
    union { u16 u[4]; uint2 q; } pk;
    __hip_bfloat16 hb;
    hb = __float2bfloat16(v.x); pk.u[0] = *(u16*)&hb;
    hb = __float2bfloat16(v.y); pk.u[1] = *(u16*)&hb;
    hb = __float2bfloat16(v.z); pk.u[2] = *(u16*)&hb;
    hb = __float2bfloat16(v.w); pk.u[3] = *(u16*)&hb;
    *(uint2*)&wqh[row * HH + col] = pk.q;
    return;
  }
  const float* src = (zi == 0) ? Wqs1 : (zi == 1) ? Wqs2 : (zi == 2) ? Wr1 : Wk;
  u16* dst = (zi == 0) ? w1t : (zi == 1) ? w2t : (zi == 2) ? wr1t : wkt;
  __shared__ float tile[32][33];
  int n0 = blockIdx.x * 32, k0 = blockIdx.y * 32;
  {
    int kk = t >> 3, nn = (t & 7) * 4;
    float4 v = *(const float4*)&src[(k0 + kk) * HH + n0 + nn];
    tile[kk][nn + 0] = v.x;
    tile[kk][nn + 1] = v.y;
    tile[kk][nn + 2] = v.z;
    tile[kk][nn + 3] = v.w;
  }
  __syncthreads();
  {
    int nn = t >> 3, kk = (t & 7) * 4;
    union { u16 u[4]; uint2 q; } pk;
#pragma unroll
    for (int i = 0; i < 4; ++i) {
      __hip_bfloat16 hb = __float2bfloat16(tile[kk + i][nn]);
      pk.u[i] = *(u16*)&hb;
    }
    *(uint2*)&dst[(n0 + nn) * HH + k0 + kk] = pk.q;
  }
}

// ---- k1_mfma helpers: BM=64, 8 waves (2m x 4n), per-wave 32x64 output ----
__device__ __forceinline__ void g_gemm(const u16* aLb, const u16* __restrict__ Bg,
                                       int wm, int wn, int lg, int lr,
                                       f32x4 acc[2][4]) {
#pragma unroll
  for (int k0 = 0; k0 < HH; k0 += 32) {
    int colb = (k0 + (lg << 3)) << 1;
    bf16x8 af[2];
#pragma unroll
    for (int mi = 0; mi < 2; ++mi) {
      int row = wm * 32 + mi * 16 + lr;
      af[mi] = *(const bf16x8*)((const char*)aLb + (row << 9) +
                                (colb ^ ((row & 7) << 4)));
    }
    bf16x8 bfr[4];
#pragma unroll
    for (int ni = 0; ni < 4; ++ni) {
      int n = wn * 64 + ni * 16 + lr;
      bfr[ni] = *(const bf16x8*)&Bg[n * HH + k0 + (lg << 3)];
    }
#pragma unroll
    for (int mi = 0; mi < 2; ++mi)
#pragma unroll
      for (int ni = 0; ni < 4; ++ni)
        acc[mi][ni] = __builtin_amdgcn_mfma_f32_16x16x32_bf16(af[mi], bfr[ni], acc[mi][ni], 0, 0, 0);
  }
}

__device__ __forceinline__ void c_write(u16* xLb, f32x4 acc[2][4],
                                        const float* __restrict__ bias, bool dorelu,
                                        int wm, int wn, int lg, int lr) {
#pragma unroll
  for (int ni = 0; ni < 4; ++ni) {
    int col = wn * 64 + ni * 16 + lr;
    float bv = bias ? bias[col] : 0.f;
#pragma unroll
    for (int mi = 0; mi < 2; ++mi) {
#pragma unroll
      for (int j = 0; j < 4; ++j) {
        int row = wm * 32 + mi * 16 + (lg << 2) + j;
        float v = acc[mi][ni][j] + bv;
        if (dorelu) v = fmaxf(v, 0.f);
        __hip_bfloat16 hb = __float2bfloat16(v);
        *(u16*)((char*)xLb + (row << 9) + (((col << 1)) ^ ((row & 7) << 4))) = *(u16*)&hb;
      }
    }
  }
}

// K1: fused MLP chain via MFMA. BM=64, grid 75, 512 threads.
__global__ __launch_bounds__(512) void k1_mfma(
    const u16* __restrict__ proh, const float* __restrict__ posx,
    const float* __restrict__ bbox,
    const u16* __restrict__ w1t, const u16* __restrict__ w2t,
    const u16* __restrict__ wr1t, const u16* __restrict__ wkt,
    const u16* __restrict__ wqh,
    const float* __restrict__ bqs1, const float* __restrict__ bqs2,
    const float* __restrict__ br1, const float* __restrict__ Wr2,
    const float* __restrict__ br2, const float* __restrict__ bq,
    float* __restrict__ z, float* __restrict__ c1) {
  __shared__ u16 aL[16384];   // [64][512B] swz: pro, later px
  __shared__ u16 xL[16384];   // r1 -> t1 -> y
  __shared__ float red0[512], red1[512];
  __shared__ float scLoL[64], scHiL[64];
  const int t = threadIdx.x;
  const int w = t >> 6, l = t & 63;
  const int lg = l >> 4, lr = l & 15;
  const int wm = w >> 2, wn = w & 3;
  const int m0 = blockIdx.x * 64;

#pragma unroll
  for (int i = 0; i < 4; ++i) {
    int c = i * 512 + t;
    int a = c * 16;
    int row = a >> 9, x0 = a & 511;
    int src = (m0 + row) * HH + ((x0 ^ ((row & 7) << 4)) >> 1);
    load_lds16(proh + src, (char*)aL + (size_t)(i * 512 + (w << 6)) * 16);
  }
  __syncthreads();

  // G3: r1 = relu(pro @ Wr1 + br1) -> xL
  {
    f32x4 acc[2][4] = {};
    g_gemm(aL, wr1t, wm, wn, lg, lr, acc);
    c_write(xL, acc, br1, true, wm, wn, lg, lr);
  }
  __syncthreads();
  // G4: ref = sigmoid(r1 @ Wr2 + br2); per-row scales
  {
    int row = t & 63, seg = t >> 6;
    float s0 = 0.f, s1 = 0.f;
#pragma unroll 8
    for (int hh = 0; hh < 32; ++hh) {
      int h = seg * 32 + hh;
      float rv = bf2f(*(const __hip_bfloat16*)((const char*)xL + (row << 9) +
                                               (((h << 1)) ^ ((row & 7) << 4))));
      s0 = fmaf(rv, Wr2[h * 2 + 0], s0);
      s1 = fmaf(rv, Wr2[h * 2 + 1], s1);
    }
    red0[row * 8 + seg] = s0;
    red1[row * 8 + seg] = s1;
  }
  __syncthreads();
  if (t < 64) {
    float s0 = br2[0], s1 = br2[1];
#pragma unroll
    for (int k = 0; k < 8; ++k) {
      s0 += red0[t * 8 + k];
      s1 += red1[t * 8 + k];
    }
    float r0 = 1.f / (1.f + __expf(-s0));
    float r1 = 1.f / (1.f + __expf(-s1));
    scHiL[t] = r0 / bbox[(m0 + t) * 4 + 2];
    scLoL[t] = r1 / bbox[(m0 + t) * 4 + 3];
  }
  // G1: t1 = relu(pro @ Wqs1 + bqs1) -> xL (after barrier)
  f32x4 acc1[2][4] = {};
  g_gemm(aL, w1t, wm, wn, lg, lr, acc1);
  __syncthreads();
  c_write(xL, acc1, bqs1, true, wm, wn, lg, lr);
  __syncthreads();
  // G2: pos_t = t1 @ Wqs2 (+bqs2 later) -> regs
  f32x4 accp[2][4] = {};
  g_gemm(xL, w2t, wm, wn, lg, lr, accp);
  __syncthreads();
  // scale: px = posx * (pos_t+bqs2) * sc -> aL
#pragma unroll
  for (int ni = 0; ni < 4; ++ni) {
    int col = wn * 64 + ni * 16 + lr;
    float bv = bqs2[col];
#pragma unroll
    for (int mi = 0; mi < 2; ++mi) {
#pragma unroll
      for (int j = 0; j < 4; ++j) {
        int row = wm * 32 + mi * 16 + (lg << 2) + j;
        float pt = accp[mi][ni][j] + bv;
        float sc = (col < 128) ? scLoL[row] : scHiL[row];
        float v = posx[(m0 + row) * HH + col] * pt * sc;
        __hip_bfloat16 hb = __float2bfloat16(v);
        *(u16*)((char*)aL + (row << 9) + (((col << 1)) ^ ((row & 7) << 4))) = *(u16*)&hb;
      }
    }
  }
  __syncthreads();
  // G5: y = px @ Wk -> xL
  {
    f32x4 acc[2][4] = {};
    g_gemm(aL, wkt, wm, wn, lg, lr, acc);
    c_write(xL, acc, nullptr, false, wm, wn, lg, lr);
  }
  __syncthreads();
  // c1 partials + G6: z = y @ Wq^T
  {
    int row = t & 63, seg = t >> 6;
    float s0 = 0.f;
#pragma unroll 8
    for (int hh = 0; hh < 32; ++hh) {
      int h = seg * 32 + hh;
      float yv = bf2f(*(const __hip_bfloat16*)((const char*)xL + (row << 9) +
                                               (((h << 1)) ^ ((row & 7) << 4))));
      s0 = fmaf(yv, bq[h], s0);
    }
    red0[row * 8 + seg] = s0;
  }
  f32x4 accz[2][4] = {};
  g_gemm(xL, wqh, wm, wn, lg, lr, accz);
  __syncthreads();
  if (t < 64) {
    float s = 0.f;
#pragma unroll
    for (int k = 0; k < 8; ++k) s += red0[t * 8 + k];
    c1[m0 + t] = s;
  }
#pragma unroll
  for (int ni = 0; ni < 4; ++ni) {
    int col = wn * 64 + ni * 16 + lr;
#pragma unroll
    for (int mi = 0; mi < 2; ++mi) {
#pragma unroll
      for (int j = 0; j < 4; ++j) {
        int row = wm * 32 + mi * 16 + (lg << 2) + j;
        z[(size_t)(m0 + row) * HH + col] = accz[mi][ni][j];
      }
    }
  }
}

// K2: fp[b,s] = posl[s]*(pos_img[s,b]·z[b] + c1[b]) + pos_img[s,b]·w2 + c2
__global__ __launch_bounds__(256) void k2_fp(
    const float* __restrict__ posi, const float* __restrict__ posl,
    const float* __restrict__ z, const float* __restrict__ c1,
    const float* __restrict__ w2c2, float* __restrict__ fp) {
  int b = blockIdx.x, t = threadIdx.x;
  int l = t & 63, w = t >> 6;
  float4 zv = *(const float4*)&z[b * HH + l * 4];
  float4 wv = *(const float4*)&w2c2[l * 4];
  float c1b = c1[b];
  float c2 = w2c2[HH];
  for (int s = w; s < SS; s += 4) {
    float4 pi = *(const float4*)&posi[((size_t)s * BB + b) * HH + l * 4];
    float d1 = pi.x * zv.x + pi.y * zv.y + pi.z * zv.z + pi.w * zv.w;
    float d2 = pi.x * wv.x + pi.y * wv.y + pi.z * wv.z + pi.w * wv.w;
#pragma unroll
    for (int off = 32; off > 0; off >>= 1) {
      d1 += __shfl_xor(d1, off);
      d2 += __shfl_xor(d2, off);
    }
    if (l == 0) fp[b * SS + s] = posl[s] * (d1 + c1b) + d2 + c2;
  }
}

// cast pro -> bf16, padded to MPAD rows (zeros in pad)
__global__ __launch_bounds__(256) void kc_pro(const float* __restrict__ pro,
                                              u16* __restrict__ proh) {
  int tg = blockIdx.x * 256 + threadIdx.x;
  int e0 = tg * 8;
  int row = e0 >> 8;
  union { u16 u[8]; uint4 v; } pk;
  if (row < BB) {
    float4 v0 = *(const float4*)&pro[e0];
    float4 v1 = *(const float4*)&pro[e0 + 4];
    float vv[8] = {v0.x, v0.y, v0.z, v0.w, v1.x, v1.y, v1.z, v1.w};
#pragma unroll
    for (int i = 0; i < 8; ++i) {
      __hip_bfloat16 hb = __float2bfloat16(vv[i]);
      pk.u[i] = *(u16*)&hb;
    }
  } else {
    pk.v = make_uint4(0, 0, 0, 0);
  }
  *(uint4*)&proh[e0] = pk.v;
}

// transpose+cast Wd (256 x 32768 f32) -> wdt[nperm(n)][k] bf16
__global__ __launch_bounds__(256) void kc_wdt(const float* __restrict__ Wd,
                                              u16* __restrict__ wdt) {
  __shared__ float tile[32][33];
  int n0 = blockIdx.x * 32;
  int k0 = blockIdx.y * 32;
  int t = threadIdx.x;
  {
    int kk = t >> 3, nn = (t & 7) * 4;
    float4 v = *(const float4*)&Wd[(size_t)(k0 + kk) * NDP + n0 + nn];
    tile[kk][nn + 0] = v.x;
    tile[kk][nn + 1] = v.y;
    tile[kk][nn + 2] = v.z;
    tile[kk][nn + 3] = v.w;
  }
  __syncthreads();
  {
    int nn = t >> 3, kk = (t & 7) * 4;
    union { u16 u[4]; uint2 v; } pk;
#pragma unroll
    for (int i = 0; i < 4; ++i) {
      __hip_bfloat16 hb = __float2bfloat16(tile[kk + i][nn]);
      pk.u[i] = *(u16*)&hb;
    }
    int np = nperm(n0 + nn);
    *(uint2*)&wdt[(size_t)np * HH + k0 + kk] = pk.v;
  }
}

// bdp[nperm(n)] = bd[n]
__global__ void kc_bdp(const float* __restrict__ bd, float* __restrict__ bdp) {
  int n = blockIdx.x * 256 + threadIdx.x;
  bdp[nperm(n)] = bd[n];
}

// transpose+cast Wo (12544 x 256 f32) -> woT (256 x 12544 bf16)
__global__ __launch_bounds__(256) void kc_wot(const float* __restrict__ Wo,
                                              u16* __restrict__ wot) {
  __shared__ float tile[32][33];
  int k0 = blockIdx.x * 32;
  int n0 = blockIdx.y * 32;
  int t = threadIdx.x;
  {
    int kk = t >> 3, nn = (t & 7) * 4;
    float4 v = *(const float4*)&Wo[(size_t)(k0 + kk) * HH + n0 + nn];
    tile[kk][nn + 0] = v.x;
    tile[kk][nn + 1] = v.y;
    tile[kk][nn + 2] = v.z;
    tile[kk][nn + 3] = v.w;
  }
  __syncthreads();
  {
    int nn = t >> 3, kk = (t & 7) * 4;
    union { u16 u[4]; uint2 v; } pk;
#pragma unroll
    for (int i = 0; i < 4; ++i) {
      __hip_bfloat16 hb = __float2bfloat16(tile[kk + i][nn]);
      pk.u[i] = *(u16*)&hb;
    }
    *(uint2*)&wot[(size_t)(n0 + nn) * KWO + k0 + kk] = pk.v;
  }
}

// K3: params = proh @ wdt^T + bdp via bf16 MFMA. M=4800(pad 4864), N=32768, K=256.
// r8 structure + 2-phase pipeline: double-buffered staging, issue next tile's
// global_load_lds BEFORE computing current, one barrier per K-step.
__global__ __launch_bounds__(256) void k3_mfma(const u16* __restrict__ proh,
                                               const u16* __restrict__ wdt,
                                               const float* __restrict__ bdp,
                                               u16* __restrict__ params) {
  __shared__ char smem[32768];  // buf0: A@0 B@8K; buf1: A@16K B@24K; epilogue C = all 32K
  const int t = threadIdx.x;
  const int w = t >> 6, l = t & 63;
  const int n0 = blockIdx.x * 128;
  const int m0 = blockIdx.y * 128;
  const int wr = w >> 1, wc = w & 1;
  f32x4 acc[4][4] = {};

  // stage K-step ks into buffer buf
  auto stage = [&](int buf, int k0) {
    u16* Ab = (u16*)(smem + buf * 16384);
    u16* Bb = Ab + 4096;
#pragma unroll
    for (int i = 0; i < 2; ++i) {
      int c = i * 256 + t;
      int r = c >> 2, kq = (c & 3) * 8;
      int wbase = (i * 256 + (w << 6)) * 8;
      load_lds16(proh + (size_t)(m0 + r) * HH + k0 + kq, Ab + wbase);
      load_lds16(wdt + (size_t)(n0 + r) * HH + k0 + kq, Bb + wbase);
    }
  };

  stage(0, 0);
  __syncthreads();
  for (int ks = 0; ks < 8; ++ks) {
    int cur = ks & 1;
    if (ks < 7) stage(cur ^ 1, (ks + 1) * 32);
    const u16* Al = (const u16*)(smem + cur * 16384);
    const u16* Bl = Al + 4096;
    bf16x8 af[4], bfr[4];
#pragma unroll
    for (int mi = 0; mi < 4; ++mi)
      af[mi] = *(const bf16x8*)&Al[(wr * 64 + mi * 16 + (l & 15)) * 32 + (l >> 4) * 8];
#pragma unroll
    for (int ni = 0; ni < 4; ++ni)
      bfr[ni] = *(const bf16x8*)&Bl[(wc * 64 + ni * 16 + (l & 15)) * 32 + (l >> 4) * 8];
#pragma unroll
    for (int mi = 0; mi < 4; ++mi)
#pragma unroll
      for (int ni = 0; ni < 4; ++ni)
        acc[mi][ni] = __builtin_amdgcn_mfma_f32_16x16x32_bf16(af[mi], bfr[ni], acc[mi][ni], 0, 0, 0);
    __syncthreads();  // drains next-stage vmcnt + protects buffer reuse
  }
  // epilogue: bias + bf16 -> LDS tile (overlays both buffers), coalesced stores
  u16* cb = (u16*)smem;
#pragma unroll
  for (int ni = 0; ni < 4; ++ni) {
    int col = wc * 64 + ni * 16 + (l & 15);
    float bias = bdp[n0 + col];
#pragma unroll
    for (int mi = 0; mi < 4; ++mi) {
#pragma unroll
      for (int j = 0; j < 4; ++j) {
        int row = wr * 64 + mi * 16 + ((l >> 4) << 2) + j;
        __hip_bfloat16 hb = __float2bfloat16(acc[mi][ni][j] + bias);
        cb[row * 128 + col] = *(u16*)&hb;
      }
    }
  }
  __syncthreads();
#pragma unroll
  for (int i = 0; i < 8; ++i) {
    int idx = i * 256 + t;
    int row = idx >> 4, cc = (idx & 15) * 8;
    if (m0 + row < BB)
      *(uint4*)&params[(size_t)(m0 + row) * NDP + n0 + cc] = *(const uint4*)&cb[row * 128 + cc];
  }
}

// K4: per-b dynamic conv via MFMA. Halved staging: bufP 16KB + bufF 16KB (as u16 cnt).
__global__ __launch_bounds__(256) void k4_mfma(
    const float* __restrict__ roi, const u16* __restrict__ params,
    const float* __restrict__ fpbuf,
    const float* __restrict__ g1, const float* __restrict__ be1,
    const float* __restrict__ g2, const float* __restrict__ be2,
    u16* __restrict__ f2ws) {
  __shared__ u16 bufP[8192];  // p1 h-half [64 d][128 h] swz(256B); later p2 h-half [128 h][64 d] swz(128B)
  __shared__ u16 bufF[8192];  // feat h-half [64 s][128 h] swz(256B); later f1L [64 s][64 d] swz(128B)
  __shared__ float fpL[64];
  __shared__ float g1L[64], b1L[64], g2L[256], b2L[256];

  const int b = blockIdx.x;
  const int t = threadIdx.x;
  const int w = t >> 6, l = t & 63;
  const int lg = l >> 4, lr = l & 15;
  const u16* p1g = params + (size_t)b * NDP;        // [64][256]
  const u16* p2g = params + (size_t)b * NDP + PP;   // [256][64]

  f32x4 acc1[4] = {};
#pragma unroll
  for (int half = 0; half < 2; ++half) {
    const int hoff = half * 128;
#pragma unroll
    for (int i = 0; i < 4; ++i) {
      int c = i * 256 + t;
      int row = c >> 4, x0 = (c & 15) * 16;
      load_lds16(p1g + row * HH + hoff + ((x0 ^ ((row & 7) << 4)) >> 1),
                 (char*)bufP + (size_t)(i * 256 + (w << 6)) * 16);
    }
#pragma unroll
    for (int i = 0; i < 8; ++i) {
      int idx = i * 256 + t;
      int row = idx >> 5, c4 = (idx & 31) << 2;
      union { u16 u[4]; unsigned long long v; } pk;
      if (row < SS) {
        float4 v = *(const float4*)&roi[((size_t)row * BB + b) * HH + hoff + c4];
        __hip_bfloat16 h0 = __float2bfloat16(v.x), h1 = __float2bfloat16(v.y);
        __hip_bfloat16 h2 = __float2bfloat16(v.z), h3 = __float2bfloat16(v.w);
        pk.u[0] = *(u16*)&h0; pk.u[1] = *(u16*)&h1;
        pk.u[2] = *(u16*)&h2; pk.u[3] = *(u16*)&h3;
      } else {
        pk.v = 0ull;
      }
      int ab = (row << 8) + (((c4 << 1)) ^ ((row & 7) << 4));
      *(unsigned long long*)((char*)bufF + ab) = pk.v;
    }
    if (half == 0) {
      if (t < 64) {
        fpL[t] = (t < SS) ? fpbuf[b * SS + t] : 0.f;
        g1L[t] = g1[t];
        b1L[t] = be1[t];
      }
      g2L[t] = g2[t];
      b2L[t] = be2[t];
    }
    __syncthreads();
#pragma unroll
    for (int kk = 0; kk < 128; kk += 32) {
      int arow = w * 16 + lr;
      const bf16x8 af = *(const bf16x8*)((const char*)bufF + (arow << 8) +
                                         ((((kk + (lg << 3)) << 1)) ^ ((arow & 7) << 4)));
      bf16x8 bfr[4];
#pragma unroll
      for (int ni = 0; ni < 4; ++ni) {
        int brow = ni * 16 + lr;
        bfr[ni] = *(const bf16x8*)((const char*)bufP + (brow << 8) +
                                   ((((kk + (lg << 3)) << 1)) ^ ((brow & 7) << 4)));
      }
#pragma unroll
      for (int ni = 0; ni < 4; ++ni)
        acc1[ni] = __builtin_amdgcn_mfma_f32_16x16x32_bf16(af, bfr[ni], acc1[ni], 0, 0, 0);
    }
    __syncthreads();
  }

#pragma unroll
  for (int i = 0; i < 4; ++i) {
    int c = i * 256 + t;
    int row = c >> 3, x0 = (c & 7) * 16;
    load_lds16(p2g + row * DD + ((x0 ^ ((row & 7) << 4)) >> 1),
               (char*)bufP + (size_t)(i * 256 + (w << 6)) * 16);
  }

  u16* f1L = bufF;
#pragma unroll
  for (int j = 0; j < 4; ++j) {
    int s = w * 16 + (lg << 2) + j;
    float fpv = fpL[s];
    float x[4], sum = 0.f, sq = 0.f;
#pragma unroll
    for (int ni = 0; ni < 4; ++ni) {
      x[ni] = acc1[ni][j] + fpv;
      sum += x[ni];
      sq += x[ni] * x[ni];
    }
#pragma unroll
    for (int off = 1; off < 16; off <<= 1) {
      sum += __shfl_xor(sum, off);
      sq += __shfl_xor(sq, off);
    }
    float m = sum * (1.f / 64.f);
    float rs = rsqrtf(sq * (1.f / 64.f) - m * m + 1e-5f);
#pragma unroll
    for (int ni = 0; ni < 4; ++ni) {
      int d = ni * 16 + lr;
      float o = fmaxf((x[ni] - m) * rs * g1L[d] + b1L[d], 0.f);
      __hip_bfloat16 hb = __float2bfloat16(o);
      *(u16*)((char*)f1L + (s << 7) + ((d << 1) ^ ((s & 7) << 4))) = *(u16*)&hb;
    }
  }
  __syncthreads();

  f32x4 acc2[16] = {};
#pragma unroll
  for (int nh = 0; nh < 2; ++nh) {
    if (nh == 1) {
      __syncthreads();
#pragma unroll
      for (int i = 0; i < 4; ++i) {
        int c = i * 256 + t;
        int row = c >> 3, x0 = (c & 7) * 16;
        load_lds16(p2g + (128 + row) * DD + ((x0 ^ ((row & 7) << 4)) >> 1),
                   (char*)bufP + (size_t)(i * 256 + (w << 6)) * 16);
      }
      __syncthreads();
    }
#pragma unroll
    for (int kk = 0; kk < 64; kk += 32) {
      int arow = w * 16 + lr;
      const bf16x8 af = *(const bf16x8*)((const char*)f1L + (arow << 7) +
                                         ((((kk + (lg << 3)) << 1)) ^ ((arow & 7) << 4)));
#pragma unroll
      for (int ni = 0; ni < 8; ++ni) {
        int brow = ni * 16 + lr;
        const bf16x8 bfr = *(const bf16x8*)((const char*)bufP + (brow << 7) +
                                            ((((kk + (lg << 3)) << 1)) ^ ((brow & 7) << 4)));
        acc2[nh * 8 + ni] = __builtin_amdgcn_mfma_f32_16x16x32_bf16(af, bfr, acc2[nh * 8 + ni], 0, 0, 0);
      }
    }
  }

#pragma unroll
  for (int j = 0; j < 4; ++j) {
    int s = w * 16 + (lg << 2) + j;
    float sum = 0.f, sq = 0.f;
#pragma unroll
    for (int ni = 0; ni < 16; ++ni) {
      float v = acc2[ni][j];
      sum += v;
      sq += v * v;
    }
#pragma unroll
    for (int off = 1; off < 16; off <<= 1) {
      sum += __shfl_xor(sum, off);
      sq += __shfl_xor(sq, off);
    }
    float m = sum * (1.f / 256.f);
    float rs = rsqrtf(sq * (1.f / 256.f) - m * m + 1e-5f);
    if (s < SS) {
#pragma unroll
      for (int ni = 0; ni < 16; ++ni) {
        int h = ni * 16 + lr;
        float o = fmaxf((acc2[ni][j] - m) * rs * g2L[h] + b2L[h], 0.f);
        __hip_bfloat16 hb = __float2bfloat16(o);
        f2ws[(size_t)b * KWO + s * HH + h] = *(u16*)&hb;
      }
    }
  }
}

// K5: partial[sk][m][0..256) = f2ws[m, kchunk] @ woT^T, split-K bf16 MFMA.
// BM=64, BN=256, BK=32; 2-phase pipeline (dbuf + issue-before-compute).
__global__ __launch_bounds__(256) void k5_mfma(const u16* __restrict__ f2,
                                               const u16* __restrict__ wot,
                                               float* __restrict__ part) {
  __shared__ char smem[40960];  // buf: A 4KB + B 16KB = 20KB, x2
  const int t = threadIdx.x;
  const int w = t >> 6, l = t & 63;
  const int lg = l >> 4, lr = l & 15;
  const int sk = blockIdx.x;
  const int m0 = blockIdx.y * 64;
  const size_t kbase = (size_t)sk * KCH;
  const int wr = w >> 1, wc = w & 1;
  f32x4 acc[2][8] = {};

  auto stage = [&](int buf, int k0) {
    u16* Al = (u16*)(smem + buf * 20480);
    u16* Bl = Al + 2048;
    {
      int r = t >> 2, kq = (t & 3) * 8;
      int wbase = (w << 6) * 8;
      load_lds16(f2 + (size_t)(m0 + r) * KWO + kbase + k0 + kq, Al + wbase);
    }
#pragma unroll
    for (int i = 0; i < 4; ++i) {
      int c = i * 256 + t;
      int r = c >> 2, kq = (c & 3) * 8;
      int wbase = (i * 256 + (w << 6)) * 8;
      load_lds16(wot + (size_t)r * KWO + kbase + k0 + kq, Bl + wbase);
    }
  };

  stage(0, 0);
  __syncthreads();
  for (int ks = 0; ks < 49; ++ks) {
    int cur = ks & 1;
    if (ks < 48) stage(cur ^ 1, (ks + 1) * 32);
    const u16* Al = (const u16*)(smem + cur * 20480);
    const u16* Bl = Al + 2048;
    bf16x8 af[2], bfr[8];
#pragma unroll
    for (int mi = 0; mi < 2; ++mi)
      af[mi] = *(const bf16x8*)&Al[(wr * 32 + mi * 16 + lr) * 32 + lg * 8];
#pragma unroll
    for (int ni = 0; ni < 8; ++ni)
      bfr[ni] = *(const bf16x8*)&Bl[(wc * 128 + ni * 16 + lr) * 32 + lg * 8];
#pragma unroll
    for (int mi = 0; mi < 2; ++mi)
#pragma unroll
      for (int ni = 0; ni < 8; ++ni)
        acc[mi][ni] = __builtin_amdgcn_mfma_f32_16x16x32_bf16(af[mi], bfr[ni], acc[mi][ni], 0, 0, 0);
    __syncthreads();
  }
#pragma unroll
  for (int mi = 0; mi < 2; ++mi) {
#pragma unroll
    for (int j = 0; j < 4; ++j) {
      int m = m0 + wr * 32 + mi * 16 + (lg << 2) + j;
#pragma unroll
      for (int ni = 0; ni < 8; ++ni) {
        int n = wc * 128 + ni * 16 + lr;
        part[((size_t)sk * BB + m) * HH + n] = acc[mi][ni][j];
      }
    }
  }
}

// K5R: reduce partials + bias, LN3 + relu -> out
__global__ __launch_bounds__(256) void k5r_ln3(
    const float* __restrict__ part, const float* __restrict__ bo,
    const float* __restrict__ g3, const float* __restrict__ be3,
    float* __restrict__ out) {
  __shared__ float red[4];
  int b = blockIdx.x, t = threadIdx.x;
  float v = bo[t];
#pragma unroll
  for (int sk = 0; sk < SK; ++sk) v += part[((size_t)sk * BB + b) * HH + t];
  float m = block_sum256(v, red) * (1.f / HH);
  float d = v - m;
  float var = block_sum256(d * d, red) * (1.f / HH);
  out[b * HH + t] = fmaxf(fmaf(d * rsqrtf(var + 1e-5f), g3[t], be3[t]), 0.f);
}

extern "C" void kernel_launch(void* const* d_in, const int* in_sizes, int n_in,
                              void* d_out, int out_size, void* d_ws, size_t ws_size,
                              hipStream_t stream) {
  const float* pro  = (const float*)d_in[0];
  const float* roi  = (const float*)d_in[1];
  const float* posx = (const float*)d_in[2];
  const float* posi = (const float*)d_in[3];
  const float* posl = (const float*)d_in[4];
  const float* bbox = (const float*)d_in[5];
  const float* Wd   = (const float*)d_in[6];
  const float* bd   = (const float*)d_in[7];
  const float* Wqs1 = (const float*)d_in[8];
  const float* bqs1 = (const float*)d_in[9];
  const float* Wqs2 = (const float*)d_in[10];
  const float* bqs2 = (const float*)d_in[11];
  const float* Wr1  = (const float*)d_in[12];
  const float* br1  = (const float*)d_in[13];
  const float* Wr2  = (const float*)d_in[14];
  const float* br2  = (const float*)d_in[15];
  const float* Wq   = (const float*)d_in[16];
  const float* bq   = (const float*)d_in[17];
  const float* Wk   = (const float*)d_in[18];
  const float* bk   = (const float*)d_in[19];
  const float* g1   = (const float*)d_in[20];
  const float* be1  = (const float*)d_in[21];
  const float* g2   = (const float*)d_in[22];
  const float* be2  = (const float*)d_in[23];
  const float* g3   = (const float*)d_in[24];
  const float* be3  = (const float*)d_in[25];
  const float* Wo   = (const float*)d_in[26];
  const float* bo   = (const float*)d_in[27];

  char* ws = (char*)d_ws;
  u16* w1t  = (u16*)(ws + 0ull);
  u16* w2t  = (u16*)(ws + 131072ull);
  u16* wr1t = (u16*)(ws + 262144ull);
  u16* wkt  = (u16*)(ws + 393216ull);
  u16* wqh  = (u16*)(ws + 524288ull);
  u16* params = (u16*)(ws + 0ull);
  float* part = (float*)(ws + 0ull);
  u16* f2ws   = (u16*)(ws + 314572800ull);
  u16* proh   = (u16*)(ws + 314572800ull);
  u16* wdt    = (u16*)(ws + 317063168ull);
  float* z    = (float*)(ws + 434995200ull);
  u16* wot    = (u16*)(ws + 434995200ull);
  float* bdp  = (float*)(ws + 441417728ull);
  float* fp   = (float*)(ws + 444825600ull);
  float* c1   = (float*)(ws + 445766400ull);
  float* w2c2 = (float*)(ws + 446047744ull);

  kc_pro<<<dim3(MPAD * HH / 8 / 256), dim3(256), 0, stream>>>(pro, proh);
  kc_w1<<<dim3(8, 8, 5), dim3(256), 0, stream>>>(Wqs1, Wqs2, Wr1, Wk, Wq,
                                                 w1t, w2t, wr1t, wkt, wqh);
  k0_prep<<<dim3(256), dim3(256), 0, stream>>>(Wq, bk, bq, w2c2);
  k1_mfma<<<dim3(BB / 64), dim3(512), 0, stream>>>(proh, posx, bbox, w1t, w2t, wr1t,
                                                   wkt, wqh, bqs1, bqs2, br1, Wr2,
                                                   br2, bq, z, c1);
  k2_fp<<<dim3(BB), dim3(256), 0, stream>>>(posi, posl, z, c1, w2c2, fp);
  // z dead; wot overlays it
  kc_wot<<<dim3(KWO / 32, HH / 32), dim3(256), 0, stream>>>(Wo, wot);
  kc_wdt<<<dim3(NDP / 32, HH / 32), dim3(256), 0, stream>>>(Wd, wdt);
  kc_bdp<<<dim3(NDP / 256), dim3(256), 0, stream>>>(bd, bdp);
  // k1 weights dead; k3 overwrites params region
  k3_mfma<<<dim3(NDP / 128, MPAD / 128), dim3(256), 0, stream>>>(proh, wdt, bdp, params);
  k4_mfma<<<dim3(BB), dim3(256), 0, stream>>>(roi, params, fp, g1, be1, g2, be2, f2ws);
  // params dead; part overlays it
  k5_mfma<<<dim3(SK, BB / 64), dim3(256), 0, stream>>>(f2ws, wot, part);
  k5r_ln3<<<dim3(BB), dim3(256), 0, stream>>>(part, bo, g3, be3, (float*)d_out);
}

// Round 14
// 542.557 us; speedup vs baseline: 1.0373x; 1.0004x over previous
//
#include <hip/hip_runtime.h>
#include <hip/hip_bf16.h>

#define HH 256
#define DD 64
#define SS 49
#define BB 4800
#define PP 16384
#define NDP 32768
#define KWO 12544  // S*H
#define MPAD 4864  // BB padded to 128
#define SK 8       // split-K factor for K5
#define KCH 1568   // KWO / SK = 49 * 32

typedef unsigned int u32;
typedef unsigned short u16;
typedef __attribute__((ext_vector_type(8))) short bf16x8;
typedef __attribute__((ext_vector_type(4))) float f32x4;

__device__ __forceinline__ float bf2f(__hip_bfloat16 h) { return __bfloat162float(h); }

__device__ __forceinline__ void load_lds16(const void* g, void* l) {
  __builtin_amdgcn_global_load_lds(
      (const __attribute__((address_space(1))) unsigned int*)g,
      (__attribute__((address_space(3))) unsigned int*)l, 16, 0, 0);
}

// permutation of the params N-dim: param1 (n=h*64+d) -> [d][h]; param2 -> [h][d]
__device__ __forceinline__ int nperm(int n) {
  if (n < PP) { int h = n >> 6, d = n & 63; return d * HH + h; }
  int r = n - PP; int d = r >> 8, h = r & 255; return PP + h * DD + d;
}

__device__ __forceinline__ float wave_sum64(float v) {
#pragma unroll
  for (int off = 32; off > 0; off >>= 1) v += __shfl_xor(v, off);
  return v;
}

__device__ __forceinline__ float block_sum256(float v, float* red) {
  v = wave_sum64(v);
  int w = threadIdx.x >> 6;
  if ((threadIdx.x & 63) == 0) red[w] = v;
  __syncthreads();
  float r = red[0] + red[1] + red[2] + red[3];
  __syncthreads();
  return r;
}

// K0: w2[k] = sum_h Wq[k][h]*bk[h]; c2 = sum_h bq[h]*bk[h]
__global__ void k0_prep(const float* __restrict__ Wq, const float* __restrict__ bk,
                        const float* __restrict__ bq, float* __restrict__ w2c2) {
  __shared__ float red[4];
  int k = blockIdx.x, h = threadIdx.x;
  float v = Wq[k * HH + h];
  float s = block_sum256(v * bk[h], red);
  if (h == 0) w2c2[k] = s;
  if (k == 0) {
    float s2 = block_sum256(bq[h] * bk[h], red);
    if (h == 0) w2c2[HH] = s2;
  }
}

// Prep k1 weights: z=0..3 transpose+cast {Wqs1,Wqs2,Wr1,Wk} -> [n][k] bf16; z=4 cast Wq.
__global__ __launch_bounds__(256) void kc_w1(
    const float* __restrict__ Wqs1, const float* __restrict__ Wqs2,
    const float* __restrict__ Wr1, const float* __restrict__ Wk,
    const float* __restrict__ Wq,
    u16* __restrict__ w1t, u16* __restrict__ w2t, u16* __restrict__ wr1t,
    u16* __restrict__ wkt, u16* __restrict__ wqh) {
  int t = threadIdx.x;
  int zi = blockIdx.z;
  if (zi == 4) {
    int row = blockIdx.y * 32 + (t >> 3), col = blockIdx.x * 32 + (t & 7) * 4;
    float4 v = *(const float4*)&Wq[row * HH + col];
    union { u16 u[4]; uint2 q; } pk;
    __hip_bfloat16 hb;
    hb = __float2bfloat16(v.x); pk.u[0] = *(u16*)&hb;
    hb = __float2bfloat16(v.y); pk.u[1] = *(u16*)&hb;
    hb = __float2bfloat16(v.z); pk.u[2] = *(u16*)&hb;
    hb = __float2bfloat16(v.w); pk.u[3] = *(u16*)&hb;
    *(uint2*)&wqh[row * HH + col] = pk.q;
    return;
  }
  const float* src = (zi == 0) ? Wqs1 : (zi == 1) ? Wqs2 : (zi == 2) ? Wr1 : Wk;
  u16* dst = (zi == 0) ? w1t : (zi == 1) ? w2t : (zi == 2) ? wr1t : wkt;
  __shared__ float tile[32][33];
  int n0 = blockIdx.x * 32, k0 = blockIdx.y * 32;
  {
    int kk = t >> 3, nn = (t & 7) * 4;
    float4 v = *(const float4*)&src[(k0 + kk) * HH + n0 + nn];
    tile[kk][nn + 0] = v.x;
    tile[kk][nn + 1] = v.y;
    tile[kk][nn + 2] = v.z;
    tile[kk][nn + 3] = v.w;
  }
  __syncthreads();
  {
    int nn = t >> 3, kk = (t & 7) * 4;
    union { u16 u[4]; uint2 q; } pk;
#pragma unroll
    for (int i = 0; i < 4; ++i) {
      __hip_bfloat16 hb = __float2bfloat16(tile[kk + i][nn]);
      pk.u[i] = *(u16*)&hb;
    }
    *(uint2*)&dst[(n0 + nn) * HH + k0 + kk] = pk.q;
  }
}

// ---- k1_mfma helpers: BM=64, 8 waves (2m x 4n), per-wave 32x64 output ----
__device__ __forceinline__ void g_gemm(const u16* aLb, const u16* __restrict__ Bg,
                                       int wm, int wn, int lg, int lr,
                                       f32x4 acc[2][4]) {
#pragma unroll
  for (int k0 = 0; k0 < HH; k0 += 32) {
    int colb = (k0 + (lg << 3)) << 1;
    bf16x8 af[2];
#pragma unroll
    for (int mi = 0; mi < 2; ++mi) {
      int row = wm * 32 + mi * 16 + lr;
      af[mi] = *(const bf16x8*)((const char*)aLb + (row << 9) +
                                (colb ^ ((row & 7) << 4)));
    }
    bf16x8 bfr[4];
#pragma unroll
    for (int ni = 0; ni < 4; ++ni) {
      int n = wn * 64 + ni * 16 + lr;
      bfr[ni] = *(const bf16x8*)&Bg[n * HH + k0 + (lg << 3)];
    }
#pragma unroll
    for (int mi = 0; mi < 2; ++mi)
#pragma unroll
      for (int ni = 0; ni < 4; ++ni)
        acc[mi][ni] = __builtin_amdgcn_mfma_f32_16x16x32_bf16(af[mi], bfr[ni], acc[mi][ni], 0, 0, 0);
  }
}

__device__ __forceinline__ void c_write(u16* xLb, f32x4 acc[2][4],
                                        const float* __restrict__ bias, bool dorelu,
                                        int wm, int wn, int lg, int lr) {
#pragma unroll
  for (int ni = 0; ni < 4; ++ni) {
    int col = wn * 64 + ni * 16 + lr;
    float bv = bias ? bias[col] : 0.f;
#pragma unroll
    for (int mi = 0; mi < 2; ++mi) {
#pragma unroll
      for (int j = 0; j < 4; ++j) {
        int row = wm * 32 + mi * 16 + (lg << 2) + j;
        float v = acc[mi][ni][j] + bv;
        if (dorelu) v = fmaxf(v, 0.f);
        __hip_bfloat16 hb = __float2bfloat16(v);
        *(u16*)((char*)xLb + (row << 9) + (((col << 1)) ^ ((row & 7) << 4))) = *(u16*)&hb;
      }
    }
  }
}

// K1: fused MLP chain via MFMA. BM=64, grid 75, 512 threads.
__global__ __launch_bounds__(512) void k1_mfma(
    const u16* __restrict__ proh, const float* __restrict__ posx,
    const float* __restrict__ bbox,
    const u16* __restrict__ w1t, const u16* __restrict__ w2t,
    const u16* __restrict__ wr1t, const u16* __restrict__ wkt,
    const u16* __restrict__ wqh,
    const float* __restrict__ bqs1, const float* __restrict__ bqs2,
    const float* __restrict__ br1, const float* __restrict__ Wr2,
    const float* __restrict__ br2, const float* __restrict__ bq,
    float* __restrict__ z, float* __restrict__ c1) {
  __shared__ u16 aL[16384];   // [64][512B] swz: pro, later px
  __shared__ u16 xL[16384];   // r1 -> t1 -> y
  __shared__ float red0[512], red1[512];
  __shared__ float scLoL[64], scHiL[64];
  const int t = threadIdx.x;
  const int w = t >> 6, l = t & 63;
  const int lg = l >> 4, lr = l & 15;
  const int wm = w >> 2, wn = w & 3;
  const int m0 = blockIdx.x * 64;

#pragma unroll
  for (int i = 0; i < 4; ++i) {
    int c = i * 512 + t;
    int a = c * 16;
    int row = a >> 9, x0 = a & 511;
    int src = (m0 + row) * HH + ((x0 ^ ((row & 7) << 4)) >> 1);
    load_lds16(proh + src, (char*)aL + (size_t)(i * 512 + (w << 6)) * 16);
  }
  __syncthreads();

  // G3: r1 = relu(pro @ Wr1 + br1) -> xL
  {
    f32x4 acc[2][4] = {};
    g_gemm(aL, wr1t, wm, wn, lg, lr, acc);
    c_write(xL, acc, br1, true, wm, wn, lg, lr);
  }
  __syncthreads();
  // G4: ref = sigmoid(r1 @ Wr2 + br2); per-row scales
  {
    int row = t & 63, seg = t >> 6;
    float s0 = 0.f, s1 = 0.f;
#pragma unroll 8
    for (int hh = 0; hh < 32; ++hh) {
      int h = seg * 32 + hh;
      float rv = bf2f(*(const __hip_bfloat16*)((const char*)xL + (row << 9) +
                                               (((h << 1)) ^ ((row & 7) << 4))));
      s0 = fmaf(rv, Wr2[h * 2 + 0], s0);
      s1 = fmaf(rv, Wr2[h * 2 + 1], s1);
    }
    red0[row * 8 + seg] = s0;
    red1[row * 8 + seg] = s1;
  }
  __syncthreads();
  if (t < 64) {
    float s0 = br2[0], s1 = br2[1];
#pragma unroll
    for (int k = 0; k < 8; ++k) {
      s0 += red0[t * 8 + k];
      s1 += red1[t * 8 + k];
    }
    float r0 = 1.f / (1.f + __expf(-s0));
    float r1 = 1.f / (1.f + __expf(-s1));
    scHiL[t] = r0 / bbox[(m0 + t) * 4 + 2];
    scLoL[t] = r1 / bbox[(m0 + t) * 4 + 3];
  }
  // G1: t1 = relu(pro @ Wqs1 + bqs1) -> xL (after barrier)
  f32x4 acc1[2][4] = {};
  g_gemm(aL, w1t, wm, wn, lg, lr, acc1);
  __syncthreads();
  c_write(xL, acc1, bqs1, true, wm, wn, lg, lr);
  __syncthreads();
  // G2: pos_t = t1 @ Wqs2 (+bqs2 later) -> regs
  f32x4 accp[2][4] = {};
  g_gemm(xL, w2t, wm, wn, lg, lr, accp);
  __syncthreads();
  // scale: px = posx * (pos_t+bqs2) * sc -> aL
#pragma unroll
  for (int ni = 0; ni < 4; ++ni) {
    int col = wn * 64 + ni * 16 + lr;
    float bv = bqs2[col];
#pragma unroll
    for (int mi = 0; mi < 2; ++mi) {
#pragma unroll
      for (int j = 0; j < 4; ++j) {
        int row = wm * 32 + mi * 16 + (lg << 2) + j;
        float pt = accp[mi][ni][j] + bv;
        float sc = (col < 128) ? scLoL[row] : scHiL[row];
        float v = posx[(m0 + row) * HH + col] * pt * sc;
        __hip_bfloat16 hb = __float2bfloat16(v);
        *(u16*)((char*)aL + (row << 9) + (((col << 1)) ^ ((row & 7) << 4))) = *(u16*)&hb;
      }
    }
  }
  __syncthreads();
  // G5: y = px @ Wk -> xL
  {
    f32x4 acc[2][4] = {};
    g_gemm(aL, wkt, wm, wn, lg, lr, acc);
    c_write(xL, acc, nullptr, false, wm, wn, lg, lr);
  }
  __syncthreads();
  // c1 partials + G6: z = y @ Wq^T
  {
    int row = t & 63, seg = t >> 6;
    float s0 = 0.f;
#pragma unroll 8
    for (int hh = 0; hh < 32; ++hh) {
      int h = seg * 32 + hh;
      float yv = bf2f(*(const __hip_bfloat16*)((const char*)xL + (row << 9) +
                                               (((h << 1)) ^ ((row & 7) << 4))));
      s0 = fmaf(yv, bq[h], s0);
    }
    red0[row * 8 + seg] = s0;
  }
  f32x4 accz[2][4] = {};
  g_gemm(xL, wqh, wm, wn, lg, lr, accz);
  __syncthreads();
  if (t < 64) {
    float s = 0.f;
#pragma unroll
    for (int k = 0; k < 8; ++k) s += red0[t * 8 + k];
    c1[m0 + t] = s;
  }
#pragma unroll
  for (int ni = 0; ni < 4; ++ni) {
    int col = wn * 64 + ni * 16 + lr;
#pragma unroll
    for (int mi = 0; mi < 2; ++mi) {
#pragma unroll
      for (int j = 0; j < 4; ++j) {
        int row = wm * 32 + mi * 16 + (lg << 2) + j;
        z[(size_t)(m0 + row) * HH + col] = accz[mi][ni][j];
      }
    }
  }
}

// K2: fp[b,s] = posl[s]*(pos_img[s,b]·z[b] + c1[b]) + pos_img[s,b]·w2 + c2
__global__ __launch_bounds__(256) void k2_fp(
    const float* __restrict__ posi, const float* __restrict__ posl,
    const float* __restrict__ z, const float* __restrict__ c1,
    const float* __restrict__ w2c2, float* __restrict__ fp) {
  int b = blockIdx.x, t = threadIdx.x;
  int l = t & 63, w = t >> 6;
  float4 zv = *(const float4*)&z[b * HH + l * 4];
  float4 wv = *(const float4*)&w2c2[l * 4];
  float c1b = c1[b];
  float c2 = w2c2[HH];
  for (int s = w; s < SS; s += 4) {
    float4 pi = *(const float4*)&posi[((size_t)s * BB + b) * HH + l * 4];
    float d1 = pi.x * zv.x + pi.y * zv.y + pi.z * zv.z + pi.w * zv.w;
    float d2 = pi.x * wv.x + pi.y * wv.y + pi.z * wv.z + pi.w * wv.w;
#pragma unroll
    for (int off = 32; off > 0; off >>= 1) {
      d1 += __shfl_xor(d1, off);
      d2 += __shfl_xor(d2, off);
    }
    if (l == 0) fp[b * SS + s] = posl[s] * (d1 + c1b) + d2 + c2;
  }
}

// cast pro -> bf16, padded to MPAD rows (zeros in pad)
__global__ __launch_bounds__(256) void kc_pro(const float* __restrict__ pro,
                                              u16* __restrict__ proh) {
  int tg = blockIdx.x * 256 + threadIdx.x;
  int e0 = tg * 8;
  int row = e0 >> 8;
  union { u16 u[8]; uint4 v; } pk;
  if (row < BB) {
    float4 v0 = *(const float4*)&pro[e0];
    float4 v1 = *(const float4*)&pro[e0 + 4];
    float vv[8] = {v0.x, v0.y, v0.z, v0.w, v1.x, v1.y, v1.z, v1.w};
#pragma unroll
    for (int i = 0; i < 8; ++i) {
      __hip_bfloat16 hb = __float2bfloat16(vv[i]);
      pk.u[i] = *(u16*)&hb;
    }
  } else {
    pk.v = make_uint4(0, 0, 0, 0);
  }
  *(uint4*)&proh[e0] = pk.v;
}

// transpose+cast Wd (256 x 32768 f32) -> wdt[nperm(n)][k] bf16
__global__ __launch_bounds__(256) void kc_wdt(const float* __restrict__ Wd,
                                              u16* __restrict__ wdt) {
  __shared__ float tile[32][33];
  int n0 = blockIdx.x * 32;
  int k0 = blockIdx.y * 32;
  int t = threadIdx.x;
  {
    int kk = t >> 3, nn = (t & 7) * 4;
    float4 v = *(const float4*)&Wd[(size_t)(k0 + kk) * NDP + n0 + nn];
    tile[kk][nn + 0] = v.x;
    tile[kk][nn + 1] = v.y;
    tile[kk][nn + 2] = v.z;
    tile[kk][nn + 3] = v.w;
  }
  __syncthreads();
  {
    int nn = t >> 3, kk = (t & 7) * 4;
    union { u16 u[4]; uint2 v; } pk;
#pragma unroll
    for (int i = 0; i < 4; ++i) {
      __hip_bfloat16 hb = __float2bfloat16(tile[kk + i][nn]);
      pk.u[i] = *(u16*)&hb;
    }
    int np = nperm(n0 + nn);
    *(uint2*)&wdt[(size_t)np * HH + k0 + kk] = pk.v;
  }
}

// bdp[nperm(n)] = bd[n]
__global__ void kc_bdp(const float* __restrict__ bd, float* __restrict__ bdp) {
  int n = blockIdx.x * 256 + threadIdx.x;
  bdp[nperm(n)] = bd[n];
}

// transpose+cast Wo (12544 x 256 f32) -> woT (256 x 12544 bf16)
__global__ __launch_bounds__(256) void kc_wot(const float* __restrict__ Wo,
                                              u16* __restrict__ wot) {
  __shared__ float tile[32][33];
  int k0 = blockIdx.x * 32;
  int n0 = blockIdx.y * 32;
  int t = threadIdx.x;
  {
    int kk = t >> 3, nn = (t & 7) * 4;
    float4 v = *(const float4*)&Wo[(size_t)(k0 + kk) * HH + n0 + nn];
    tile[kk][nn + 0] = v.x;
    tile[kk][nn + 1] = v.y;
    tile[kk][nn + 2] = v.z;
    tile[kk][nn + 3] = v.w;
  }
  __syncthreads();
  {
    int nn = t >> 3, kk = (t & 7) * 4;
    union { u16 u[4]; uint2 v; } pk;
#pragma unroll
    for (int i = 0; i < 4; ++i) {
      __hip_bfloat16 hb = __float2bfloat16(tile[kk + i][nn]);
      pk.u[i] = *(u16*)&hb;
    }
    *(uint2*)&wot[(size_t)(n0 + nn) * KWO + k0 + kk] = pk.v;
  }
}

// K3: params = proh @ wdt^T + bdp via bf16 MFMA. 2-phase pipeline (r13).
__global__ __launch_bounds__(256) void k3_mfma(const u16* __restrict__ proh,
                                               const u16* __restrict__ wdt,
                                               const float* __restrict__ bdp,
                                               u16* __restrict__ params) {
  __shared__ char smem[32768];  // buf0: A@0 B@8K; buf1: A@16K B@24K; epilogue C = all 32K
  const int t = threadIdx.x;
  const int w = t >> 6, l = t & 63;
  const int n0 = blockIdx.x * 128;
  const int m0 = blockIdx.y * 128;
  const int wr = w >> 1, wc = w & 1;
  f32x4 acc[4][4] = {};

  auto stage = [&](int buf, int k0) {
    u16* Ab = (u16*)(smem + buf * 16384);
    u16* Bb = Ab + 4096;
#pragma unroll
    for (int i = 0; i < 2; ++i) {
      int c = i * 256 + t;
      int r = c >> 2, kq = (c & 3) * 8;
      int wbase = (i * 256 + (w << 6)) * 8;
      load_lds16(proh + (size_t)(m0 + r) * HH + k0 + kq, Ab + wbase);
      load_lds16(wdt + (size_t)(n0 + r) * HH + k0 + kq, Bb + wbase);
    }
  };

  stage(0, 0);
  __syncthreads();
  for (int ks = 0; ks < 8; ++ks) {
    int cur = ks & 1;
    if (ks < 7) stage(cur ^ 1, (ks + 1) * 32);
    const u16* Al = (const u16*)(smem + cur * 16384);
    const u16* Bl = Al + 4096;
    bf16x8 af[4], bfr[4];
#pragma unroll
    for (int mi = 0; mi < 4; ++mi)
      af[mi] = *(const bf16x8*)&Al[(wr * 64 + mi * 16 + (l & 15)) * 32 + (l >> 4) * 8];
#pragma unroll
    for (int ni = 0; ni < 4; ++ni)
      bfr[ni] = *(const bf16x8*)&Bl[(wc * 64 + ni * 16 + (l & 15)) * 32 + (l >> 4) * 8];
#pragma unroll
    for (int mi = 0; mi < 4; ++mi)
#pragma unroll
      for (int ni = 0; ni < 4; ++ni)
        acc[mi][ni] = __builtin_amdgcn_mfma_f32_16x16x32_bf16(af[mi], bfr[ni], acc[mi][ni], 0, 0, 0);
    __syncthreads();
  }
  u16* cb = (u16*)smem;
#pragma unroll
  for (int ni = 0; ni < 4; ++ni) {
    int col = wc * 64 + ni * 16 + (l & 15);
    float bias = bdp[n0 + col];
#pragma unroll
    for (int mi = 0; mi < 4; ++mi) {
#pragma unroll
      for (int j = 0; j < 4; ++j) {
        int row = wr * 64 + mi * 16 + ((l >> 4) << 2) + j;
        __hip_bfloat16 hb = __float2bfloat16(acc[mi][ni][j] + bias);
        cb[row * 128 + col] = *(u16*)&hb;
      }
    }
  }
  __syncthreads();
#pragma unroll
  for (int i = 0; i < 8; ++i) {
    int idx = i * 256 + t;
    int row = idx >> 4, cc = (idx & 15) * 8;
    if (m0 + row < BB)
      *(uint4*)&params[(size_t)(m0 + row) * NDP + n0 + cc] = *(const uint4*)&cb[row * 128 + cc];
  }
}

// K4: per-b dynamic conv via MFMA. Quarter staging: bufP 8KB + bufF 8KB -> ~19KB LDS
// -> 8 blocks/CU (occupancy cap) for latency hiding.
__global__ __launch_bounds__(256) void k4_mfma(
    const float* __restrict__ roi, const u16* __restrict__ params,
    const float* __restrict__ fpbuf,
    const float* __restrict__ g1, const float* __restrict__ be1,
    const float* __restrict__ g2, const float* __restrict__ be2,
    u16* __restrict__ f2ws) {
  __shared__ u16 bufP[4096];  // p1 h-qtr [64 d][64 h] swz(128B); later p2 h-qtr [64 h][64 d] swz(128B)
  __shared__ u16 bufF[4096];  // feat h-qtr [64 s][64 h] swz(128B); later f1L [64 s][64 d] swz(128B)
  __shared__ float fpL[64];
  __shared__ float g1L[64], b1L[64], g2L[256], b2L[256];

  const int b = blockIdx.x;
  const int t = threadIdx.x;
  const int w = t >> 6, l = t & 63;
  const int lg = l >> 4, lr = l & 15;
  const u16* p1g = params + (size_t)b * NDP;        // [64][256]
  const u16* p2g = params + (size_t)b * NDP + PP;   // [256][64]

  f32x4 acc1[4] = {};
#pragma unroll
  for (int q = 0; q < 4; ++q) {
    const int hoff = q * 64;
    // stage p1 h-quarter: 512 chunks of 16B, 2/thread; 128B rows, swizzled source
#pragma unroll
    for (int i = 0; i < 2; ++i) {
      int c = i * 256 + t;
      int row = c >> 3, x0 = (c & 7) * 16;
      load_lds16(p1g + row * HH + hoff + ((x0 ^ ((row & 7) << 4)) >> 1),
                 (char*)bufP + (size_t)(i * 256 + (w << 6)) * 16);
    }
    // feat h-quarter: fp32 -> bf16, swizzled ds_write (128B rows)
#pragma unroll
    for (int i = 0; i < 4; ++i) {
      int idx = i * 256 + t;           // float4-units over 64 rows x 16
      int row = idx >> 4, c4 = (idx & 15) << 2;
      union { u16 u[4]; unsigned long long v; } pk;
      if (row < SS) {
        float4 v = *(const float4*)&roi[((size_t)row * BB + b) * HH + hoff + c4];
        __hip_bfloat16 h0 = __float2bfloat16(v.x), h1 = __float2bfloat16(v.y);
        __hip_bfloat16 h2 = __float2bfloat16(v.z), h3 = __float2bfloat16(v.w);
        pk.u[0] = *(u16*)&h0; pk.u[1] = *(u16*)&h1;
        pk.u[2] = *(u16*)&h2; pk.u[3] = *(u16*)&h3;
      } else {
        pk.v = 0ull;
      }
      int ab = (row << 7) + (((c4 << 1)) ^ ((row & 7) << 4));
      *(unsigned long long*)((char*)bufF + ab) = pk.v;
    }
    if (q == 0) {
      if (t < 64) {
        fpL[t] = (t < SS) ? fpbuf[b * SS + t] : 0.f;
        g1L[t] = g1[t];
        b1L[t] = be1[t];
      }
      g2L[t] = g2[t];
      b2L[t] = be2[t];
    }
    __syncthreads();
    // f1 partial GEMM over this h-quarter (K=64): M=64 s, N=64 d
#pragma unroll
    for (int kk = 0; kk < 64; kk += 32) {
      int arow = w * 16 + lr;
      const bf16x8 af = *(const bf16x8*)((const char*)bufF + (arow << 7) +
                                         ((((kk + (lg << 3)) << 1)) ^ ((arow & 7) << 4)));
      bf16x8 bfr[4];
#pragma unroll
      for (int ni = 0; ni < 4; ++ni) {
        int brow = ni * 16 + lr;
        bfr[ni] = *(const bf16x8*)((const char*)bufP + (brow << 7) +
                                   ((((kk + (lg << 3)) << 1)) ^ ((brow & 7) << 4)));
      }
#pragma unroll
      for (int ni = 0; ni < 4; ++ni)
        acc1[ni] = __builtin_amdgcn_mfma_f32_16x16x32_bf16(af, bfr[ni], acc1[ni], 0, 0, 0);
    }
    __syncthreads();  // reads done; next quarter (or p2/f1L) overwrites
  }

  // issue p2 quarter0 stage into bufP ([64 h][64 d], 128B rows); hides under LN1
#pragma unroll
  for (int i = 0; i < 2; ++i) {
    int c = i * 256 + t;
    int row = c >> 3, x0 = (c & 7) * 16;
    load_lds16(p2g + row * DD + ((x0 ^ ((row & 7) << 4)) >> 1),
               (char*)bufP + (size_t)(i * 256 + (w << 6)) * 16);
  }

  // LN1 + relu -> f1L (overlay bufF; 128B rows, swizzled)
  u16* f1L = bufF;
#pragma unroll
  for (int j = 0; j < 4; ++j) {
    int s = w * 16 + (lg << 2) + j;
    float fpv = fpL[s];
    float x[4], sum = 0.f, sq = 0.f;
#pragma unroll
    for (int ni = 0; ni < 4; ++ni) {
      x[ni] = acc1[ni][j] + fpv;
      sum += x[ni];
      sq += x[ni] * x[ni];
    }
#pragma unroll
    for (int off = 1; off < 16; off <<= 1) {
      sum += __shfl_xor(sum, off);
      sq += __shfl_xor(sq, off);
    }
    float m = sum * (1.f / 64.f);
    float rs = rsqrtf(sq * (1.f / 64.f) - m * m + 1e-5f);
#pragma unroll
    for (int ni = 0; ni < 4; ++ni) {
      int d = ni * 16 + lr;
      float o = fmaxf((x[ni] - m) * rs * g1L[d] + b1L[d], 0.f);
      __hip_bfloat16 hb = __float2bfloat16(o);
      *(u16*)((char*)f1L + (s << 7) + ((d << 1) ^ ((s & 7) << 4))) = *(u16*)&hb;
    }
  }
  __syncthreads();  // f1L written, p2 q0 arrived

  // f2 = f1 @ param2: M=64 s, N=256 h in 4 quarters of 64, K=64 d.
  f32x4 acc2[16] = {};
#pragma unroll
  for (int nq = 0; nq < 4; ++nq) {
    if (nq > 0) {
      __syncthreads();  // prev quarter reads done
#pragma unroll
      for (int i = 0; i < 2; ++i) {
        int c = i * 256 + t;
        int row = c >> 3, x0 = (c & 7) * 16;
        load_lds16(p2g + (nq * 64 + row) * DD + ((x0 ^ ((row & 7) << 4)) >> 1),
                   (char*)bufP + (size_t)(i * 256 + (w << 6)) * 16);
      }
      __syncthreads();
    }
#pragma unroll
    for (int kk = 0; kk < 64; kk += 32) {
      int arow = w * 16 + lr;
      const bf16x8 af = *(const bf16x8*)((const char*)f1L + (arow << 7) +
                                         ((((kk + (lg << 3)) << 1)) ^ ((arow & 7) << 4)));
#pragma unroll
      for (int ni = 0; ni < 4; ++ni) {
        int brow = ni * 16 + lr;
        const bf16x8 bfr = *(const bf16x8*)((const char*)bufP + (brow << 7) +
                                            ((((kk + (lg << 3)) << 1)) ^ ((brow & 7) << 4)));
        acc2[nq * 4 + ni] = __builtin_amdgcn_mfma_f32_16x16x32_bf16(af, bfr, acc2[nq * 4 + ni], 0, 0, 0);
      }
    }
  }

  // LN2 + relu -> f2ws  (acc2[m] maps to h = (m>>2)*64 + (m&3)*16 + lr)
#pragma unroll
  for (int j = 0; j < 4; ++j) {
    int s = w * 16 + (lg << 2) + j;
    float sum = 0.f, sq = 0.f;
#pragma unroll
    for (int ni = 0; ni < 16; ++ni) {
      float v = acc2[ni][j];
      sum += v;
      sq += v * v;
    }
#pragma unroll
    for (int off = 1; off < 16; off <<= 1) {
      sum += __shfl_xor(sum, off);
      sq += __shfl_xor(sq, off);
    }
    float m = sum * (1.f / 256.f);
    float rs = rsqrtf(sq * (1.f / 256.f) - m * m + 1e-5f);
    if (s < SS) {
#pragma unroll
      for (int ni = 0; ni < 16; ++ni) {
        int h = (ni >> 2) * 64 + (ni & 3) * 16 + lr;
        float o = fmaxf((acc2[ni][j] - m) * rs * g2L[h] + b2L[h], 0.f);
        __hip_bfloat16 hb = __float2bfloat16(o);
        f2ws[(size_t)b * KWO + s * HH + h] = *(u16*)&hb;
      }
    }
  }
}

// K5: partial[sk][m][0..256) = f2ws[m, kchunk] @ woT^T, split-K bf16 MFMA.
// BM=64, BN=256, BK=32; 2-phase pipeline (dbuf + issue-before-compute).
__global__ __launch_bounds__(256) void k5_mfma(const u16* __restrict__ f2,
                                               const u16* __restrict__ wot,
                                               float* __restrict__ part) {
  __shared__ char smem[40960];  // buf: A 4KB + B 16KB = 20KB, x2
  const int t = threadIdx.x;
  const int w = t >> 6, l = t & 63;
  const int lg = l >> 4, lr = l & 15;
  const int sk = blockIdx.x;
  const int m0 = blockIdx.y * 64;
  const size_t kbase = (size_t)sk * KCH;
  const int wr = w >> 1, wc = w & 1;
  f32x4 acc[2][8] = {};

  auto stage = [&](int buf, int k0) {
    u16* Al = (u16*)(smem + buf * 20480);
    u16* Bl = Al + 2048;
    {
      int r = t >> 2, kq = (t & 3) * 8;
      int wbase = (w << 6) * 8;
      load_lds16(f2 + (size_t)(m0 + r) * KWO + kbase + k0 + kq, Al + wbase);
    }
#pragma unroll
    for (int i = 0; i < 4; ++i) {
      int c = i * 256 + t;
      int r = c >> 2, kq = (c & 3) * 8;
      int wbase = (i * 256 + (w << 6)) * 8;
      load_lds16(wot + (size_t)r * KWO + kbase + k0 + kq, Bl + wbase);
    }
  };

  stage(0, 0);
  __syncthreads();
  for (int ks = 0; ks < 49; ++ks) {
    int cur = ks & 1;
    if (ks < 48) stage(cur ^ 1, (ks + 1) * 32);
    const u16* Al = (const u16*)(smem + cur * 20480);
    const u16* Bl = Al + 2048;
    bf16x8 af[2], bfr[8];
#pragma unroll
    for (int mi = 0; mi < 2; ++mi)
      af[mi] = *(const bf16x8*)&Al[(wr * 32 + mi * 16 + lr) * 32 + lg * 8];
#pragma unroll
    for (int ni = 0; ni < 8; ++ni)
      bfr[ni] = *(const bf16x8*)&Bl[(wc * 128 + ni * 16 + lr) * 32 + lg * 8];
#pragma unroll
    for (int mi = 0; mi < 2; ++mi)
#pragma unroll
      for (int ni = 0; ni < 8; ++ni)
        acc[mi][ni] = __builtin_amdgcn_mfma_f32_16x16x32_bf16(af[mi], bfr[ni], acc[mi][ni], 0, 0, 0);
    __syncthreads();
  }
#pragma unroll
  for (int mi = 0; mi < 2; ++mi) {
#pragma unroll
    for (int j = 0; j < 4; ++j) {
      int m = m0 + wr * 32 + mi * 16 + (lg << 2) + j;
#pragma unroll
      for (int ni = 0; ni < 8; ++ni) {
        int n = wc * 128 + ni * 16 + lr;
        part[((size_t)sk * BB + m) * HH + n] = acc[mi][ni][j];
      }
    }
  }
}

// K5R: reduce partials + bias, LN3 + relu -> out
__global__ __launch_bounds__(256) void k5r_ln3(
    const float* __restrict__ part, const float* __restrict__ bo,
    const float* __restrict__ g3, const float* __restrict__ be3,
    float* __restrict__ out) {
  __shared__ float red[4];
  int b = blockIdx.x, t = threadIdx.x;
  float v = bo[t];
#pragma unroll
  for (int sk = 0; sk < SK; ++sk) v += part[((size_t)sk * BB + b) * HH + t];
  float m = block_sum256(v, red) * (1.f / HH);
  float d = v - m;
  float var = block_sum256(d * d, red) * (1.f / HH);
  out[b * HH + t] = fmaxf(fmaf(d * rsqrtf(var + 1e-5f), g3[t], be3[t]), 0.f);
}

extern "C" void kernel_launch(void* const* d_in, const int* in_sizes, int n_in,
                              void* d_out, int out_size, void* d_ws, size_t ws_size,
                              hipStream_t stream) {
  const float* pro  = (const float*)d_in[0];
  const float* roi  = (const float*)d_in[1];
  const float* posx = (const float*)d_in[2];
  const float* posi = (const float*)d_in[3];
  const float* posl = (const float*)d_in[4];
  const float* bbox = (const float*)d_in[5];
  const float* Wd   = (const float*)d_in[6];
  const float* bd   = (const float*)d_in[7];
  const float* Wqs1 = (const float*)d_in[8];
  const float* bqs1 = (const float*)d_in[9];
  const float* Wqs2 = (const float*)d_in[10];
  const float* bqs2 = (const float*)d_in[11];
  const float* Wr1  = (const float*)d_in[12];
  const float* br1  = (const float*)d_in[13];
  const float* Wr2  = (const float*)d_in[14];
  const float* br2  = (const float*)d_in[15];
  const float* Wq   = (const float*)d_in[16];
  const float* bq   = (const float*)d_in[17];
  const float* Wk   = (const float*)d_in[18];
  const float* bk   = (const float*)d_in[19];
  const float* g1   = (const float*)d_in[20];
  const float* be1  = (const float*)d_in[21];
  const float* g2   = (const float*)d_in[22];
  const float* be2  = (const float*)d_in[23];
  const float* g3   = (const float*)d_in[24];
  const float* be3  = (const float*)d_in[25];
  const float* Wo   = (const float*)d_in[26];
  const float* bo   = (const float*)d_in[27];

  char* ws = (char*)d_ws;
  u16* w1t  = (u16*)(ws + 0ull);
  u16* w2t  = (u16*)(ws + 131072ull);
  u16* wr1t = (u16*)(ws + 262144ull);
  u16* wkt  = (u16*)(ws + 393216ull);
  u16* wqh  = (u16*)(ws + 524288ull);
  u16* params = (u16*)(ws + 0ull);
  float* part = (float*)(ws + 0ull);
  u16* f2ws   = (u16*)(ws + 314572800ull);
  u16* proh   = (u16*)(ws + 314572800ull);
  u16* wdt    = (u16*)(ws + 317063168ull);
  float* z    = (float*)(ws + 434995200ull);
  u16* wot    = (u16*)(ws + 434995200ull);
  float* bdp  = (float*)(ws + 441417728ull);
  float* fp   = (float*)(ws + 444825600ull);
  float* c1   = (float*)(ws + 445766400ull);
  float* w2c2 = (float*)(ws + 446047744ull);

  kc_pro<<<dim3(MPAD * HH / 8 / 256), dim3(256), 0, stream>>>(pro, proh);
  kc_w1<<<dim3(8, 8, 5), dim3(256), 0, stream>>>(Wqs1, Wqs2, Wr1, Wk, Wq,
                                                 w1t, w2t, wr1t, wkt, wqh);
  k0_prep<<<dim3(256), dim3(256), 0, stream>>>(Wq, bk, bq, w2c2);
  k1_mfma<<<dim3(BB / 64), dim3(512), 0, stream>>>(proh, posx, bbox, w1t, w2t, wr1t,
                                                   wkt, wqh, bqs1, bqs2, br1, Wr2,
                                                   br2, bq, z, c1);
  k2_fp<<<dim3(BB), dim3(256), 0, stream>>>(posi, posl, z, c1, w2c2, fp);
  // z dead; wot overlays it
  kc_wot<<<dim3(KWO / 32, HH / 32), dim3(256), 0, stream>>>(Wo, wot);
  kc_wdt<<<dim3(NDP / 32, HH / 32), dim3(256), 0, stream>>>(Wd, wdt);
  kc_bdp<<<dim3(NDP / 256), dim3(256), 0, stream>>>(bd, bdp);
  // k1 weights dead; k3 overwrites params region
  k3_mfma<<<dim3(NDP / 128, MPAD / 128), dim3(256), 0, stream>>>(proh, wdt, bdp, params);
  k4_mfma<<<dim3(BB), dim3(256), 0, stream>>>(roi, params, fp, g1, be1, g2, be2, f2ws);
  // params dead; part overlays it
  k5_mfma<<<dim3(SK, BB / 64), dim3(256), 0, stream>>>(f2ws, wot, part);
  k5r_ln3<<<dim3(BB), dim3(256), 0, stream>>>(part, bo, g3, be3, (float*)d_out);
}

// Round 15
// 531.167 us; speedup vs baseline: 1.0595x; 1.0214x over previous
//
#include <hip/hip_runtime.h>
#include <hip/hip_bf16.h>

#define HH 256
#define DD 64
#define SS 49
#define BB 4800
#define PP 16384
#define NDP 32768
#define KWO 12544  // S*H
#define MPAD 4864  // BB padded to 128
#define SK 8       // split-K factor for K5
#define KCH 1568   // KWO / SK = 49 * 32

typedef unsigned int u32;
typedef unsigned short u16;
typedef __attribute__((ext_vector_type(8))) short bf16x8;
typedef __attribute__((ext_vector_type(4))) float f32x4;

__device__ __forceinline__ float bf2f(__hip_bfloat16 h) { return __bfloat162float(h); }

__device__ __forceinline__ u16 f2bf(float v) {
  __hip_bfloat16 hb = __float2bfloat16(v);
  return *(u16*)&hb;
}

__device__ __forceinline__ void load_lds16(const void* g, void* l) {
  __builtin_amdgcn_global_load_lds(
      (const __attribute__((address_space(1))) unsigned int*)g,
      (__attribute__((address_space(3))) unsigned int*)l, 16, 0, 0);
}

// permutation of the params N-dim: param1 (n=h*64+d) -> [d][h]; param2 -> [h][d]
__device__ __forceinline__ int nperm(int n) {
  if (n < PP) { int h = n >> 6, d = n & 63; return d * HH + h; }
  int r = n - PP; int d = r >> 8, h = r & 255; return PP + h * DD + d;
}

__device__ __forceinline__ float wave_sum64(float v) {
#pragma unroll
  for (int off = 32; off > 0; off >>= 1) v += __shfl_xor(v, off);
  return v;
}

__device__ __forceinline__ float block_sum256(float v, float* red) {
  v = wave_sum64(v);
  int w = threadIdx.x >> 6;
  if ((threadIdx.x & 63) == 0) red[w] = v;
  __syncthreads();
  float r = red[0] + red[1] + red[2] + red[3];
  __syncthreads();
  return r;
}

// K0: w2[k] = sum_h Wq[k][h]*bk[h]; c2 = sum_h bq[h]*bk[h]
__global__ void k0_prep(const float* __restrict__ Wq, const float* __restrict__ bk,
                        const float* __restrict__ bq, float* __restrict__ w2c2) {
  __shared__ float red[4];
  int k = blockIdx.x, h = threadIdx.x;
  float v = Wq[k * HH + h];
  float s = block_sum256(v * bk[h], red);
  if (h == 0) w2c2[k] = s;
  if (k == 0) {
    float s2 = block_sum256(bq[h] * bk[h], red);
    if (h == 0) w2c2[HH] = s2;
  }
}

// Prep k1 weights: z=0..3 transpose+cast {Wqs1,Wqs2,Wr1,Wk} -> [n][k] bf16; z=4 cast Wq.
__global__ __launch_bounds__(256) void kc_w1(
    const float* __restrict__ Wqs1, const float* __restrict__ Wqs2,
    const float* __restrict__ Wr1, const float* __restrict__ Wk,
    const float* __restrict__ Wq,
    u16* __restrict__ w1t, u16* __restrict__ w2t, u16* __restrict__ wr1t,
    u16* __restrict__ wkt, u16* __restrict__ wqh) {
  int t = threadIdx.x;
  int zi = blockIdx.z;
  if (zi == 4) {
    int row = blockIdx.y * 32 + (t >> 3), col = blockIdx.x * 32 + (t & 7) * 4;
    float4 v = *(const float4*)&Wq[row * HH + col];
    union { u16 u[4]; uint2 q; } pk;
    pk.u[0] = f2bf(v.x); pk.u[1] = f2bf(v.y);
    pk.u[2] = f2bf(v.z); pk.u[3] = f2bf(v.w);
    *(uint2*)&wqh[row * HH + col] = pk.q;
    return;
  }
  const float* src = (zi == 0) ? Wqs1 : (zi == 1) ? Wqs2 : (zi == 2) ? Wr1 : Wk;
  u16* dst = (zi == 0) ? w1t : (zi == 1) ? w2t : (zi == 2) ? wr1t : wkt;
  __shared__ float tile[32][33];
  int n0 = blockIdx.x * 32, k0 = blockIdx.y * 32;
  {
    int kk = t >> 3, nn = (t & 7) * 4;
    float4 v = *(const float4*)&src[(k0 + kk) * HH + n0 + nn];
    tile[kk][nn + 0] = v.x;
    tile[kk][nn + 1] = v.y;
    tile[kk][nn + 2] = v.z;
    tile[kk][nn + 3] = v.w;
  }
  __syncthreads();
  {
    int nn = t >> 3, kk = (t & 7) * 4;
    union { u16 u[4]; uint2 q; } pk;
#pragma unroll
    for (int i = 0; i < 4; ++i) pk.u[i] = f2bf(tile[kk + i][nn]);
    *(uint2*)&dst[(n0 + nn) * HH + k0 + kk] = pk.q;
  }
}

// ---- k1_mfma helpers: BM=16, 4 waves (1m x 4n), per-wave 16x64 output ----
__device__ __forceinline__ void g_gemm16(const u16* aLb, const u16* __restrict__ Bg,
                                         int wn, int lg, int lr, f32x4 acc[4]) {
#pragma unroll
  for (int k0 = 0; k0 < HH; k0 += 32) {
    int colb = (k0 + (lg << 3)) << 1;
    const bf16x8 af = *(const bf16x8*)((const char*)aLb + (lr << 9) +
                                       (colb ^ ((lr & 7) << 4)));
    bf16x8 bfr[4];
#pragma unroll
    for (int ni = 0; ni < 4; ++ni) {
      int n = wn * 64 + ni * 16 + lr;
      bfr[ni] = *(const bf16x8*)&Bg[n * HH + k0 + (lg << 3)];
    }
#pragma unroll
    for (int ni = 0; ni < 4; ++ni)
      acc[ni] = __builtin_amdgcn_mfma_f32_16x16x32_bf16(af, bfr[ni], acc[ni], 0, 0, 0);
  }
}

__device__ __forceinline__ void c_write16(u16* xLb, f32x4 acc[4],
                                          const float* __restrict__ bias, bool dorelu,
                                          int wn, int lg, int lr) {
#pragma unroll
  for (int ni = 0; ni < 4; ++ni) {
    int col = wn * 64 + ni * 16 + lr;
    float bv = bias ? bias[col] : 0.f;
#pragma unroll
    for (int j = 0; j < 4; ++j) {
      int row = (lg << 2) + j;
      float v = acc[ni][j] + bv;
      if (dorelu) v = fmaxf(v, 0.f);
      *(u16*)((char*)xLb + (row << 9) + (((col << 1)) ^ ((row & 7) << 4))) = f2bf(v);
    }
  }
}

// K1: fused MLP chain via MFMA. BM=16, grid 300, 256 threads (full-chip coverage).
__global__ __launch_bounds__(256) void k1_mfma(
    const u16* __restrict__ proh, const float* __restrict__ posx,
    const float* __restrict__ bbox,
    const u16* __restrict__ w1t, const u16* __restrict__ w2t,
    const u16* __restrict__ wr1t, const u16* __restrict__ wkt,
    const u16* __restrict__ wqh,
    const float* __restrict__ bqs1, const float* __restrict__ bqs2,
    const float* __restrict__ br1, const float* __restrict__ Wr2,
    const float* __restrict__ br2, const float* __restrict__ bq,
    float* __restrict__ z, float* __restrict__ c1) {
  __shared__ u16 aL[4096];   // [16][512B] swz: pro, later px
  __shared__ u16 xL[4096];   // r1 -> t1 -> y
  __shared__ float red0[256], red1[256];
  __shared__ float scLoL[16], scHiL[16];
  const int t = threadIdx.x;
  const int w = t >> 6, l = t & 63;
  const int lg = l >> 4, lr = l & 15;
  const int wn = w;
  const int m0 = blockIdx.x * 16;

  // stage pro tile: 16 rows x 512B = 512 chunks of 16B, 2/thread
#pragma unroll
  for (int i = 0; i < 2; ++i) {
    int c = i * 256 + t;
    int a = c * 16;
    int row = a >> 9, x0 = a & 511;
    int src = (m0 + row) * HH + ((x0 ^ ((row & 7) << 4)) >> 1);
    load_lds16(proh + src, (char*)aL + (size_t)(i * 256 + (w << 6)) * 16);
  }
  __syncthreads();

  // G3: r1 = relu(pro @ Wr1 + br1) -> xL
  {
    f32x4 acc[4] = {};
    g_gemm16(aL, wr1t, wn, lg, lr, acc);
    c_write16(xL, acc, br1, true, wn, lg, lr);
  }
  __syncthreads();
  // G4: ref = sigmoid(r1 @ Wr2 + br2); per-row scales
  {
    int row = t & 15, seg = t >> 4;  // 16 segs x 16 h
    float s0 = 0.f, s1 = 0.f;
#pragma unroll
    for (int hh = 0; hh < 16; ++hh) {
      int h = seg * 16 + hh;
      float rv = bf2f(*(const __hip_bfloat16*)((const char*)xL + (row << 9) +
                                               (((h << 1)) ^ ((row & 7) << 4))));
      s0 = fmaf(rv, Wr2[h * 2 + 0], s0);
      s1 = fmaf(rv, Wr2[h * 2 + 1], s1);
    }
    red0[row * 16 + seg] = s0;
    red1[row * 16 + seg] = s1;
  }
  __syncthreads();
  if (t < 16) {
    float s0 = br2[0], s1 = br2[1];
#pragma unroll
    for (int k = 0; k < 16; ++k) {
      s0 += red0[t * 16 + k];
      s1 += red1[t * 16 + k];
    }
    float r0 = 1.f / (1.f + __expf(-s0));
    float r1 = 1.f / (1.f + __expf(-s1));
    scHiL[t] = r0 / bbox[(m0 + t) * 4 + 2];
    scLoL[t] = r1 / bbox[(m0 + t) * 4 + 3];
  }
  // G1: t1 = relu(pro @ Wqs1 + bqs1) -> xL (after barrier)
  f32x4 acc1[4] = {};
  g_gemm16(aL, w1t, wn, lg, lr, acc1);
  __syncthreads();  // G4 xL reads done; scL ready
  c_write16(xL, acc1, bqs1, true, wn, lg, lr);
  __syncthreads();
  // G2: pos_t = t1 @ Wqs2 (+bqs2 later) -> regs
  f32x4 accp[4] = {};
  g_gemm16(xL, w2t, wn, lg, lr, accp);
  __syncthreads();  // xL(t1), aL(pro) reads done
  // scale: px = posx * (pos_t+bqs2) * sc -> aL
#pragma unroll
  for (int ni = 0; ni < 4; ++ni) {
    int col = wn * 64 + ni * 16 + lr;
    float bv = bqs2[col];
#pragma unroll
    for (int j = 0; j < 4; ++j) {
      int row = (lg << 2) + j;
      float pt = accp[ni][j] + bv;
      float sc = (col < 128) ? scLoL[row] : scHiL[row];
      float v = posx[(m0 + row) * HH + col] * pt * sc;
      *(u16*)((char*)aL + (row << 9) + (((col << 1)) ^ ((row & 7) << 4))) = f2bf(v);
    }
  }
  __syncthreads();
  // G5: y = px @ Wk -> xL
  {
    f32x4 acc[4] = {};
    g_gemm16(aL, wkt, wn, lg, lr, acc);
    c_write16(xL, acc, nullptr, false, wn, lg, lr);
  }
  __syncthreads();
  // c1 partials + G6: z = y @ Wq^T
  {
    int row = t & 15, seg = t >> 4;
    float s0 = 0.f;
#pragma unroll
    for (int hh = 0; hh < 16; ++hh) {
      int h = seg * 16 + hh;
      float yv = bf2f(*(const __hip_bfloat16*)((const char*)xL + (row << 9) +
                                               (((h << 1)) ^ ((row & 7) << 4))));
      s0 = fmaf(yv, bq[h], s0);
    }
    red0[row * 16 + seg] = s0;
  }
  f32x4 accz[4] = {};
  g_gemm16(xL, wqh, wn, lg, lr, accz);
  __syncthreads();
  if (t < 16) {
    float s = 0.f;
#pragma unroll
    for (int k = 0; k < 16; ++k) s += red0[t * 16 + k];
    c1[m0 + t] = s;
  }
#pragma unroll
  for (int ni = 0; ni < 4; ++ni) {
    int col = wn * 64 + ni * 16 + lr;
#pragma unroll
    for (int j = 0; j < 4; ++j) {
      int row = (lg << 2) + j;
      z[(size_t)(m0 + row) * HH + col] = accz[ni][j];
    }
  }
}

// K2: fp[b,s] = posl[s]*(pos_img[s,b]·z[b] + c1[b]) + pos_img[s,b]·w2 + c2
__global__ __launch_bounds__(256) void k2_fp(
    const float* __restrict__ posi, const float* __restrict__ posl,
    const float* __restrict__ z, const float* __restrict__ c1,
    const float* __restrict__ w2c2, float* __restrict__ fp) {
  int b = blockIdx.x, t = threadIdx.x;
  int l = t & 63, w = t >> 6;
  float4 zv = *(const float4*)&z[b * HH + l * 4];
  float4 wv = *(const float4*)&w2c2[l * 4];
  float c1b = c1[b];
  float c2 = w2c2[HH];
  for (int s = w; s < SS; s += 4) {
    float4 pi = *(const float4*)&posi[((size_t)s * BB + b) * HH + l * 4];
    float d1 = pi.x * zv.x + pi.y * zv.y + pi.z * zv.z + pi.w * zv.w;
    float d2 = pi.x * wv.x + pi.y * wv.y + pi.z * wv.z + pi.w * wv.w;
#pragma unroll
    for (int off = 32; off > 0; off >>= 1) {
      d1 += __shfl_xor(d1, off);
      d2 += __shfl_xor(d2, off);
    }
    if (l == 0) fp[b * SS + s] = posl[s] * (d1 + c1b) + d2 + c2;
  }
}

// cast pro -> bf16, padded to MPAD rows (zeros in pad)
__global__ __launch_bounds__(256) void kc_pro(const float* __restrict__ pro,
                                              u16* __restrict__ proh) {
  int tg = blockIdx.x * 256 + threadIdx.x;
  int e0 = tg * 8;
  int row = e0 >> 8;
  union { u16 u[8]; uint4 v; } pk;
  if (row < BB) {
    float4 v0 = *(const float4*)&pro[e0];
    float4 v1 = *(const float4*)&pro[e0 + 4];
    float vv[8] = {v0.x, v0.y, v0.z, v0.w, v1.x, v1.y, v1.z, v1.w};
#pragma unroll
    for (int i = 0; i < 8; ++i) pk.u[i] = f2bf(vv[i]);
  } else {
    pk.v = make_uint4(0, 0, 0, 0);
  }
  *(uint4*)&proh[e0] = pk.v;
}

// transpose+cast Wd (256 x 32768 f32) -> wdt[nperm(n)][k] bf16
__global__ __launch_bounds__(256) void kc_wdt(const float* __restrict__ Wd,
                                              u16* __restrict__ wdt) {
  __shared__ float tile[32][33];
  int n0 = blockIdx.x * 32;
  int k0 = blockIdx.y * 32;
  int t = threadIdx.x;
  {
    int kk = t >> 3, nn = (t & 7) * 4;
    float4 v = *(const float4*)&Wd[(size_t)(k0 + kk) * NDP + n0 + nn];
    tile[kk][nn + 0] = v.x;
    tile[kk][nn + 1] = v.y;
    tile[kk][nn + 2] = v.z;
    tile[kk][nn + 3] = v.w;
  }
  __syncthreads();
  {
    int nn = t >> 3, kk = (t & 7) * 4;
    union { u16 u[4]; uint2 v; } pk;
#pragma unroll
    for (int i = 0; i < 4; ++i) pk.u[i] = f2bf(tile[kk + i][nn]);
    int np = nperm(n0 + nn);
    *(uint2*)&wdt[(size_t)np * HH + k0 + kk] = pk.v;
  }
}

// bdp[nperm(n)] = bd[n]
__global__ void kc_bdp(const float* __restrict__ bd, float* __restrict__ bdp) {
  int n = blockIdx.x * 256 + threadIdx.x;
  bdp[nperm(n)] = bd[n];
}

// transpose+cast Wo (12544 x 256 f32) -> woT (256 x 12544 bf16)
__global__ __launch_bounds__(256) void kc_wot(const float* __restrict__ Wo,
                                              u16* __restrict__ wot) {
  __shared__ float tile[32][33];
  int k0 = blockIdx.x * 32;
  int n0 = blockIdx.y * 32;
  int t = threadIdx.x;
  {
    int kk = t >> 3, nn = (t & 7) * 4;
    float4 v = *(const float4*)&Wo[(size_t)(k0 + kk) * HH + n0 + nn];
    tile[kk][nn + 0] = v.x;
    tile[kk][nn + 1] = v.y;
    tile[kk][nn + 2] = v.z;
    tile[kk][nn + 3] = v.w;
  }
  __syncthreads();
  {
    int nn = t >> 3, kk = (t & 7) * 4;
    union { u16 u[4]; uint2 v; } pk;
#pragma unroll
    for (int i = 0; i < 4; ++i) pk.u[i] = f2bf(tile[kk + i][nn]);
    *(uint2*)&wot[(size_t)(n0 + nn) * KWO + k0 + kk] = pk.v;
  }
}

// K3: params = proh @ wdt^T + bdp via bf16 MFMA. 2-phase pipeline (r13).
__global__ __launch_bounds__(256) void k3_mfma(const u16* __restrict__ proh,
                                               const u16* __restrict__ wdt,
                                               const float* __restrict__ bdp,
                                               u16* __restrict__ params) {
  __shared__ char smem[32768];
  const int t = threadIdx.x;
  const int w = t >> 6, l = t & 63;
  const int n0 = blockIdx.x * 128;
  const int m0 = blockIdx.y * 128;
  const int wr = w >> 1, wc = w & 1;
  f32x4 acc[4][4] = {};

  auto stage = [&](int buf, int k0) {
    u16* Ab = (u16*)(smem + buf * 16384);
    u16* Bb = Ab + 4096;
#pragma unroll
    for (int i = 0; i < 2; ++i) {
      int c = i * 256 + t;
      int r = c >> 2, kq = (c & 3) * 8;
      int wbase = (i * 256 + (w << 6)) * 8;
      load_lds16(proh + (size_t)(m0 + r) * HH + k0 + kq, Ab + wbase);
      load_lds16(wdt + (size_t)(n0 + r) * HH + k0 + kq, Bb + wbase);
    }
  };

  stage(0, 0);
  __syncthreads();
  for (int ks = 0; ks < 8; ++ks) {
    int cur = ks & 1;
    if (ks < 7) stage(cur ^ 1, (ks + 1) * 32);
    const u16* Al = (const u16*)(smem + cur * 16384);
    const u16* Bl = Al + 4096;
    bf16x8 af[4], bfr[4];
#pragma unroll
    for (int mi = 0; mi < 4; ++mi)
      af[mi] = *(const bf16x8*)&Al[(wr * 64 + mi * 16 + (l & 15)) * 32 + (l >> 4) * 8];
#pragma unroll
    for (int ni = 0; ni < 4; ++ni)
      bfr[ni] = *(const bf16x8*)&Bl[(wc * 64 + ni * 16 + (l & 15)) * 32 + (l >> 4) * 8];
#pragma unroll
    for (int mi = 0; mi < 4; ++mi)
#pragma unroll
      for (int ni = 0; ni < 4; ++ni)
        acc[mi][ni] = __builtin_amdgcn_mfma_f32_16x16x32_bf16(af[mi], bfr[ni], acc[mi][ni], 0, 0, 0);
    __syncthreads();
  }
  u16* cb = (u16*)smem;
#pragma unroll
  for (int ni = 0; ni < 4; ++ni) {
    int col = wc * 64 + ni * 16 + (l & 15);
    float bias = bdp[n0 + col];
#pragma unroll
    for (int mi = 0; mi < 4; ++mi) {
#pragma unroll
      for (int j = 0; j < 4; ++j) {
        int row = wr * 64 + mi * 16 + ((l >> 4) << 2) + j;
        cb[row * 128 + col] = f2bf(acc[mi][ni][j] + bias);
      }
    }
  }
  __syncthreads();
#pragma unroll
  for (int i = 0; i < 8; ++i) {
    int idx = i * 256 + t;
    int row = idx >> 4, cc = (idx & 15) * 8;
    if (m0 + row < BB)
      *(uint4*)&params[(size_t)(m0 + row) * NDP + n0 + cc] = *(const uint4*)&cb[row * 128 + cc];
  }
}

// K4: per-b dynamic conv via MFMA (r14 quarter-staging version, ~19KB LDS).
__global__ __launch_bounds__(256) void k4_mfma(
    const float* __restrict__ roi, const u16* __restrict__ params,
    const float* __restrict__ fpbuf,
    const float* __restrict__ g1, const float* __restrict__ be1,
    const float* __restrict__ g2, const float* __restrict__ be2,
    u16* __restrict__ f2ws) {
  __shared__ u16 bufP[4096];
  __shared__ u16 bufF[4096];
  __shared__ float fpL[64];
  __shared__ float g1L[64], b1L[64], g2L[256], b2L[256];

  const int b = blockIdx.x;
  const int t = threadIdx.x;
  const int w = t >> 6, l = t & 63;
  const int lg = l >> 4, lr = l & 15;
  const u16* p1g = params + (size_t)b * NDP;
  const u16* p2g = params + (size_t)b * NDP + PP;

  f32x4 acc1[4] = {};
#pragma unroll
  for (int q = 0; q < 4; ++q) {
    const int hoff = q * 64;
#pragma unroll
    for (int i = 0; i < 2; ++i) {
      int c = i * 256 + t;
      int row = c >> 3, x0 = (c & 7) * 16;
      load_lds16(p1g + row * HH + hoff + ((x0 ^ ((row & 7) << 4)) >> 1),
                 (char*)bufP + (size_t)(i * 256 + (w << 6)) * 16);
    }
#pragma unroll
    for (int i = 0; i < 4; ++i) {
      int idx = i * 256 + t;
      int row = idx >> 4, c4 = (idx & 15) << 2;
      union { u16 u[4]; unsigned long long v; } pk;
      if (row < SS) {
        float4 v = *(const float4*)&roi[((size_t)row * BB + b) * HH + hoff + c4];
        pk.u[0] = f2bf(v.x); pk.u[1] = f2bf(v.y);
        pk.u[2] = f2bf(v.z); pk.u[3] = f2bf(v.w);
      } else {
        pk.v = 0ull;
      }
      int ab = (row << 7) + (((c4 << 1)) ^ ((row & 7) << 4));
      *(unsigned long long*)((char*)bufF + ab) = pk.v;
    }
    if (q == 0) {
      if (t < 64) {
        fpL[t] = (t < SS) ? fpbuf[b * SS + t] : 0.f;
        g1L[t] = g1[t];
        b1L[t] = be1[t];
      }
      g2L[t] = g2[t];
      b2L[t] = be2[t];
    }
    __syncthreads();
#pragma unroll
    for (int kk = 0; kk < 64; kk += 32) {
      int arow = w * 16 + lr;
      const bf16x8 af = *(const bf16x8*)((const char*)bufF + (arow << 7) +
                                         ((((kk + (lg << 3)) << 1)) ^ ((arow & 7) << 4)));
      bf16x8 bfr[4];
#pragma unroll
      for (int ni = 0; ni < 4; ++ni) {
        int brow = ni * 16 + lr;
        bfr[ni] = *(const bf16x8*)((const char*)bufP + (brow << 7) +
                                   ((((kk + (lg << 3)) << 1)) ^ ((brow & 7) << 4)));
      }
#pragma unroll
      for (int ni = 0; ni < 4; ++ni)
        acc1[ni] = __builtin_amdgcn_mfma_f32_16x16x32_bf16(af, bfr[ni], acc1[ni], 0, 0, 0);
    }
    __syncthreads();
  }

#pragma unroll
  for (int i = 0; i < 2; ++i) {
    int c = i * 256 + t;
    int row = c >> 3, x0 = (c & 7) * 16;
    load_lds16(p2g + row * DD + ((x0 ^ ((row & 7) << 4)) >> 1),
               (char*)bufP + (size_t)(i * 256 + (w << 6)) * 16);
  }

  u16* f1L = bufF;
#pragma unroll
  for (int j = 0; j < 4; ++j) {
    int s = w * 16 + (lg << 2) + j;
    float fpv = fpL[s];
    float x[4], sum = 0.f, sq = 0.f;
#pragma unroll
    for (int ni = 0; ni < 4; ++ni) {
      x[ni] = acc1[ni][j] + fpv;
      sum += x[ni];
      sq += x[ni] * x[ni];
    }
#pragma unroll
    for (int off = 1; off < 16; off <<= 1) {
      sum += __shfl_xor(sum, off);
      sq += __shfl_xor(sq, off);
    }
    float m = sum * (1.f / 64.f);
    float rs = rsqrtf(sq * (1.f / 64.f) - m * m + 1e-5f);
#pragma unroll
    for (int ni = 0; ni < 4; ++ni) {
      int d = ni * 16 + lr;
      float o = fmaxf((x[ni] - m) * rs * g1L[d] + b1L[d], 0.f);
      *(u16*)((char*)f1L + (s << 7) + ((d << 1) ^ ((s & 7) << 4))) = f2bf(o);
    }
  }
  __syncthreads();

  f32x4 acc2[16] = {};
#pragma unroll
  for (int nq = 0; nq < 4; ++nq) {
    if (nq > 0) {
      __syncthreads();
#pragma unroll
      for (int i = 0; i < 2; ++i) {
        int c = i * 256 + t;
        int row = c >> 3, x0 = (c & 7) * 16;
        load_lds16(p2g + (nq * 64 + row) * DD + ((x0 ^ ((row & 7) << 4)) >> 1),
                   (char*)bufP + (size_t)(i * 256 + (w << 6)) * 16);
      }
      __syncthreads();
    }
#pragma unroll
    for (int kk = 0; kk < 64; kk += 32) {
      int arow = w * 16 + lr;
      const bf16x8 af = *(const bf16x8*)((const char*)f1L + (arow << 7) +
                                         ((((kk + (lg << 3)) << 1)) ^ ((arow & 7) << 4)));
#pragma unroll
      for (int ni = 0; ni < 4; ++ni) {
        int brow = ni * 16 + lr;
        const bf16x8 bfr = *(const bf16x8*)((const char*)bufP + (brow << 7) +
                                            ((((kk + (lg << 3)) << 1)) ^ ((brow & 7) << 4)));
        acc2[nq * 4 + ni] = __builtin_amdgcn_mfma_f32_16x16x32_bf16(af, bfr, acc2[nq * 4 + ni], 0, 0, 0);
      }
    }
  }

#pragma unroll
  for (int j = 0; j < 4; ++j) {
    int s = w * 16 + (lg << 2) + j;
    float sum = 0.f, sq = 0.f;
#pragma unroll
    for (int ni = 0; ni < 16; ++ni) {
      float v = acc2[ni][j];
      sum += v;
      sq += v * v;
    }
#pragma unroll
    for (int off = 1; off < 16; off <<= 1) {
      sum += __shfl_xor(sum, off);
      sq += __shfl_xor(sq, off);
    }
    float m = sum * (1.f / 256.f);
    float rs = rsqrtf(sq * (1.f / 256.f) - m * m + 1e-5f);
    if (s < SS) {
#pragma unroll
      for (int ni = 0; ni < 16; ++ni) {
        int h = (ni >> 2) * 64 + (ni & 3) * 16 + lr;
        float o = fmaxf((acc2[ni][j] - m) * rs * g2L[h] + b2L[h], 0.f);
        f2ws[(size_t)b * KWO + s * HH + h] = f2bf(o);
      }
    }
  }
}

// K5: partial[sk][m][0..256) = f2ws[m, kchunk] @ woT^T, split-K bf16 MFMA.
// BM=64, BN=256, BK=32; 2-phase pipeline; bf16 partials.
__global__ __launch_bounds__(256) void k5_mfma(const u16* __restrict__ f2,
                                               const u16* __restrict__ wot,
                                               u16* __restrict__ part) {
  __shared__ char smem[40960];
  const int t = threadIdx.x;
  const int w = t >> 6, l = t & 63;
  const int lg = l >> 4, lr = l & 15;
  const int sk = blockIdx.x;
  const int m0 = blockIdx.y * 64;
  const size_t kbase = (size_t)sk * KCH;
  const int wr = w >> 1, wc = w & 1;
  f32x4 acc[2][8] = {};

  auto stage = [&](int buf, int k0) {
    u16* Al = (u16*)(smem + buf * 20480);
    u16* Bl = Al + 2048;
    {
      int r = t >> 2, kq = (t & 3) * 8;
      int wbase = (w << 6) * 8;
      load_lds16(f2 + (size_t)(m0 + r) * KWO + kbase + k0 + kq, Al + wbase);
    }
#pragma unroll
    for (int i = 0; i < 4; ++i) {
      int c = i * 256 + t;
      int r = c >> 2, kq = (c & 3) * 8;
      int wbase = (i * 256 + (w << 6)) * 8;
      load_lds16(wot + (size_t)r * KWO + kbase + k0 + kq, Bl + wbase);
    }
  };

  stage(0, 0);
  __syncthreads();
  for (int ks = 0; ks < 49; ++ks) {
    int cur = ks & 1;
    if (ks < 48) stage(cur ^ 1, (ks + 1) * 32);
    const u16* Al = (const u16*)(smem + cur * 20480);
    const u16* Bl = Al + 2048;
    bf16x8 af[2], bfr[8];
#pragma unroll
    for (int mi = 0; mi < 2; ++mi)
      af[mi] = *(const bf16x8*)&Al[(wr * 32 + mi * 16 + lr) * 32 + lg * 8];
#pragma unroll
    for (int ni = 0; ni < 8; ++ni)
      bfr[ni] = *(const bf16x8*)&Bl[(wc * 128 + ni * 16 + lr) * 32 + lg * 8];
#pragma unroll
    for (int mi = 0; mi < 2; ++mi)
#pragma unroll
      for (int ni = 0; ni < 8; ++ni)
        acc[mi][ni] = __builtin_amdgcn_mfma_f32_16x16x32_bf16(af[mi], bfr[ni], acc[mi][ni], 0, 0, 0);
    __syncthreads();
  }
#pragma unroll
  for (int mi = 0; mi < 2; ++mi) {
#pragma unroll
    for (int j = 0; j < 4; ++j) {
      int m = m0 + wr * 32 + mi * 16 + (lg << 2) + j;
#pragma unroll
      for (int ni = 0; ni < 8; ++ni) {
        int n = wc * 128 + ni * 16 + lr;
        part[((size_t)sk * BB + m) * HH + n] = f2bf(acc[mi][ni][j]);
      }
    }
  }
}

// K5R: reduce bf16 partials + bias, LN3 + relu -> out
__global__ __launch_bounds__(256) void k5r_ln3(
    const u16* __restrict__ part, const float* __restrict__ bo,
    const float* __restrict__ g3, const float* __restrict__ be3,
    float* __restrict__ out) {
  __shared__ float red[4];
  int b = blockIdx.x, t = threadIdx.x;
  float v = bo[t];
#pragma unroll
  for (int sk = 0; sk < SK; ++sk)
    v += bf2f(*(const __hip_bfloat16*)&part[((size_t)sk * BB + b) * HH + t]);
  float m = block_sum256(v, red) * (1.f / HH);
  float d = v - m;
  float var = block_sum256(d * d, red) * (1.f / HH);
  out[b * HH + t] = fmaxf(fmaf(d * rsqrtf(var + 1e-5f), g3[t], be3[t]), 0.f);
}

extern "C" void kernel_launch(void* const* d_in, const int* in_sizes, int n_in,
                              void* d_out, int out_size, void* d_ws, size_t ws_size,
                              hipStream_t stream) {
  const float* pro  = (const float*)d_in[0];
  const float* roi  = (const float*)d_in[1];
  const float* posx = (const float*)d_in[2];
  const float* posi = (const float*)d_in[3];
  const float* posl = (const float*)d_in[4];
  const float* bbox = (const float*)d_in[5];
  const float* Wd   = (const float*)d_in[6];
  const float* bd   = (const float*)d_in[7];
  const float* Wqs1 = (const float*)d_in[8];
  const float* bqs1 = (const float*)d_in[9];
  const float* Wqs2 = (const float*)d_in[10];
  const float* bqs2 = (const float*)d_in[11];
  const float* Wr1  = (const float*)d_in[12];
  const float* br1  = (const float*)d_in[13];
  const float* Wr2  = (const float*)d_in[14];
  const float* br2  = (const float*)d_in[15];
  const float* Wq   = (const float*)d_in[16];
  const float* bq   = (const float*)d_in[17];
  const float* Wk   = (const float*)d_in[18];
  const float* bk   = (const float*)d_in[19];
  const float* g1   = (const float*)d_in[20];
  const float* be1  = (const float*)d_in[21];
  const float* g2   = (const float*)d_in[22];
  const float* be2  = (const float*)d_in[23];
  const float* g3   = (const float*)d_in[24];
  const float* be3  = (const float*)d_in[25];
  const float* Wo   = (const float*)d_in[26];
  const float* bo   = (const float*)d_in[27];

  char* ws = (char*)d_ws;
  u16* w1t  = (u16*)(ws + 0ull);
  u16* w2t  = (u16*)(ws + 131072ull);
  u16* wr1t = (u16*)(ws + 262144ull);
  u16* wkt  = (u16*)(ws + 393216ull);
  u16* wqh  = (u16*)(ws + 524288ull);
  u16* params = (u16*)(ws + 0ull);
  u16* part   = (u16*)(ws + 0ull);
  u16* f2ws   = (u16*)(ws + 314572800ull);
  u16* proh   = (u16*)(ws + 314572800ull);
  u16* wdt    = (u16*)(ws + 317063168ull);
  float* z    = (float*)(ws + 434995200ull);
  u16* wot    = (u16*)(ws + 434995200ull);
  float* bdp  = (float*)(ws + 441417728ull);
  float* fp   = (float*)(ws + 444825600ull);
  float* c1   = (float*)(ws + 445766400ull);
  float* w2c2 = (float*)(ws + 446047744ull);

  kc_pro<<<dim3(MPAD * HH / 8 / 256), dim3(256), 0, stream>>>(pro, proh);
  kc_w1<<<dim3(8, 8, 5), dim3(256), 0, stream>>>(Wqs1, Wqs2, Wr1, Wk, Wq,
                                                 w1t, w2t, wr1t, wkt, wqh);
  k0_prep<<<dim3(256), dim3(256), 0, stream>>>(Wq, bk, bq, w2c2);
  k1_mfma<<<dim3(BB / 16), dim3(256), 0, stream>>>(proh, posx, bbox, w1t, w2t, wr1t,
                                                   wkt, wqh, bqs1, bqs2, br1, Wr2,
                                                   br2, bq, z, c1);
  k2_fp<<<dim3(BB), dim3(256), 0, stream>>>(posi, posl, z, c1, w2c2, fp);
  // z dead; wot overlays it
  kc_wot<<<dim3(KWO / 32, HH / 32), dim3(256), 0, stream>>>(Wo, wot);
  kc_wdt<<<dim3(NDP / 32, HH / 32), dim3(256), 0, stream>>>(Wd, wdt);
  kc_bdp<<<dim3(NDP / 256), dim3(256), 0, stream>>>(bd, bdp);
  // k1 weights dead; k3 overwrites params region
  k3_mfma<<<dim3(NDP / 128, MPAD / 128), dim3(256), 0, stream>>>(proh, wdt, bdp, params);
  k4_mfma<<<dim3(BB), dim3(256), 0, stream>>>(roi, params, fp, g1, be1, g2, be2, f2ws);
  // params dead; part overlays it
  k5_mfma<<<dim3(SK, BB / 64), dim3(256), 0, stream>>>(f2ws, wot, part);
  k5r_ln3<<<dim3(BB), dim3(256), 0, stream>>>(part, bo, g3, be3, (float*)d_out);
}